// Round 1
// baseline (956.804 us; speedup 1.0000x reference)
//
#include <hip/hip_runtime.h>
#include <math.h>

#define NN 25600      // total nodes
#define BB 512        // graphs
#define NP 50         // nodes per graph
#define EPG 400       // edges per graph
#define EE 204800     // total edges
#define HH 8
#define CC 64
#define FF 512
#define GRUH 128
#define GRUIN 1024

__device__ __forceinline__ float wave_reduce_sum(float v) {
  #pragma unroll
  for (int m = 32; m >= 1; m >>= 1) v += __shfl_xor(v, m, 64);
  return v;
}

// we_dot[l*8+h] = sum_c We_l[h*64+c] * ae_l[h*64+c]
__global__ void k_wedot(const float* __restrict__ We1, const float* __restrict__ ae1,
                        const float* __restrict__ We2, const float* __restrict__ ae2,
                        const float* __restrict__ We3, const float* __restrict__ ae3,
                        float* __restrict__ wdot) {
  const float* We = blockIdx.x == 0 ? We1 : (blockIdx.x == 1 ? We2 : We3);
  const float* ae = blockIdx.x == 0 ? ae1 : (blockIdx.x == 1 ? ae2 : ae3);
  int head = threadIdx.x >> 6, lane = threadIdx.x & 63;
  float v = We[head * 64 + lane] * ae[head * 64 + lane];
  v = wave_reduce_sum(v);
  if (lane == 0) wdot[blockIdx.x * 8 + head] = v;
}

// Per-graph CSR by dst (local ids), plus loop_attr = mean incoming edge_attr.
__global__ void k_csr(const int* __restrict__ ei, const float* __restrict__ eattr,
                      int* __restrict__ rowp, int* __restrict__ esrc,
                      float* __restrict__ eea, float* __restrict__ lattr) {
  int g = blockIdx.x, tid = threadIdx.x;
  __shared__ int cnt[NP];
  __shared__ float esum[NP];
  __shared__ int rp[NP + 1];
  __shared__ int cur[NP];
  if (tid < NP) { cnt[tid] = 0; esum[tid] = 0.f; }
  __syncthreads();
  for (int e = tid; e < EPG; e += blockDim.x) {
    int ge = g * EPG + e;
    int dl = ei[EE + ge] - g * NP;
    atomicAdd(&cnt[dl], 1);
    atomicAdd(&esum[dl], eattr[ge]);
  }
  __syncthreads();
  if (tid == 0) {
    int s = 0;
    for (int i = 0; i < NP; i++) { rp[i] = s; cur[i] = s; s += cnt[i]; }
    rp[NP] = s;
  }
  __syncthreads();
  if (tid <= NP) rowp[g * 64 + tid] = rp[tid];
  if (tid < NP) lattr[g * NP + tid] = esum[tid] / (float)max(cnt[tid], 1);
  for (int e = tid; e < EPG; e += blockDim.x) {
    int ge = g * EPG + e;
    int sl = ei[ge] - g * NP;
    int dl = ei[EE + ge] - g * NP;
    int pos = atomicAdd(&cur[dl], 1);
    esrc[g * EPG + pos] = sl;
    eea[g * EPG + pos] = eattr[ge];
  }
}

// h1 = x @ W1  ([N,4]@[4,512])
__global__ void k_conv1(const float* __restrict__ x, const float* __restrict__ W1,
                        float* __restrict__ h) {
  int i = blockIdx.x * 256 + threadIdx.x;
  int n = i >> 9, f = i & 511;
  const float* xr = x + n * 4;
  h[i] = xr[0] * W1[f] + xr[1] * W1[512 + f] + xr[2] * W1[1024 + f] + xr[3] * W1[1536 + f];
}

// s_src[n,h], s_dst[n,h]: one wave per (n,h)
__global__ void k_dots(const float* __restrict__ h, const float* __restrict__ a_src,
                       const float* __restrict__ a_dst, float* __restrict__ ssrc,
                       float* __restrict__ sdst) {
  int wid = blockIdx.x * 4 + (threadIdx.x >> 6);
  int lane = threadIdx.x & 63;
  int n = wid >> 3, hd = wid & 7;
  float v = h[(size_t)n * FF + hd * 64 + lane];
  float s1 = wave_reduce_sum(v * a_src[hd * 64 + lane]);
  float s2 = wave_reduce_sum(v * a_dst[hd * 64 + lane]);
  if (lane == 0) { ssrc[n * 8 + hd] = s1; sdst[n * 8 + hd] = s2; }
}

// One block per (graph, head): softmax attention -> dense 50x50 A -> A @ h_tile.
// In-place safe (hin may == xout): block reads only its own (rows, head-slice)
// fully into LDS before writing the same region.
__global__ __launch_bounds__(256) void k_gat(
    const float* __restrict__ hin, float* __restrict__ xout,
    const float* __restrict__ ssrc, const float* __restrict__ sdst,
    const int* __restrict__ rowp, const int* __restrict__ esrcg,
    const float* __restrict__ eeag, const float* __restrict__ lattr,
    const float* __restrict__ wdot_all, const float* __restrict__ bias,
    int layer, int self_loops) {
  int g = blockIdx.x, hd = blockIdx.y, tid = threadIdx.x;
  __shared__ float h_tile[NP * CC];
  __shared__ float Amat[NP * NP];
  __shared__ float ssl[NP], sdl[NP], lat[NP];
  __shared__ float albuf[EPG];
  __shared__ int rp[NP + 1];
  __shared__ int es[EPG];
  __shared__ float ea[EPG];

  float wdot = wdot_all[layer * 8 + hd];
  for (int i = tid; i < NP * CC; i += 256) {
    int s = i >> 6, c = i & 63;
    h_tile[i] = hin[(size_t)(g * NP + s) * FF + hd * 64 + c];
  }
  for (int i = tid; i < EPG; i += 256) { es[i] = esrcg[g * EPG + i]; ea[i] = eeag[g * EPG + i]; }
  if (tid <= NP) rp[tid] = rowp[g * 64 + tid];
  if (tid < NP) {
    ssl[tid] = ssrc[(g * NP + tid) * 8 + hd];
    sdl[tid] = sdst[(g * NP + tid) * 8 + hd];
    lat[tid] = lattr[g * NP + tid];
  }
  for (int i = tid; i < NP * NP; i += 256) Amat[i] = 0.f;
  __syncthreads();

  if (tid < NP) {
    int d = tid;
    int e0 = rp[d], e1 = rp[d + 1];
    float sd = sdl[d];
    float m = -1e30f;
    for (int e = e0; e < e1; e++) {
      float al = ssl[es[e]] + sd + ea[e] * wdot;
      al = al > 0.f ? al : 0.2f * al;   // leaky_relu 0.2
      albuf[e] = al;
      m = fmaxf(m, al);
    }
    float al_loop = 0.f;
    if (self_loops) {
      al_loop = ssl[d] + sd + lat[d] * wdot;
      al_loop = al_loop > 0.f ? al_loop : 0.2f * al_loop;
      m = fmaxf(m, al_loop);
    }
    if (e1 > e0 || self_loops) {
      float denom = 0.f;
      for (int e = e0; e < e1; e++) { float p = expf(albuf[e] - m); albuf[e] = p; denom += p; }
      float ploop = 0.f;
      if (self_loops) { ploop = expf(al_loop - m); denom += ploop; }
      float inv = 1.f / (denom + 1e-16f);
      for (int e = e0; e < e1; e++) Amat[d * NP + es[e]] += albuf[e] * inv;
      if (self_loops) Amat[d * NP + d] += ploop * inv;
    }
  }
  __syncthreads();

  // out[d][c] = sum_s A[d][s] * h_tile[s][c]; thread: c = tid&63, d in {dg, dg+4, ...}
  int c = tid & 63, dg = tid >> 6;
  float acc[13];
  #pragma unroll
  for (int j = 0; j < 13; j++) acc[j] = 0.f;
  for (int s = 0; s < NP; s++) {
    float hv = h_tile[s * 64 + c];
    #pragma unroll
    for (int j = 0; j < 13; j++) {
      int d = dg + j * 4;
      if (d < NP) acc[j] += Amat[d * NP + s] * hv;
    }
  }
  float bb = bias[hd * 64 + c];
  #pragma unroll
  for (int j = 0; j < 13; j++) {
    int d = dg + j * 4;
    if (d < NP) xout[(size_t)(g * NP + d) * FF + hd * 64 + c] = fmaxf(acc[j] + bb, 0.f);
  }
}

// fp32 tiled GEMM: C = A[MxK] @ B[KxN] (+bias). M%64==0, N%64==0, K%16==0.
__global__ __launch_bounds__(256) void k_sgemm(
    const float* __restrict__ A, const float* __restrict__ B,
    const float* __restrict__ bias, float* __restrict__ C,
    int M, int N, int K) {
  __shared__ __align__(16) float As[16][68];
  __shared__ __align__(16) float Bs[16][64];
  int tid = threadIdx.x;
  int tx = tid & 15, ty = tid >> 4;
  int row0 = blockIdx.y * 64, col0 = blockIdx.x * 64;
  int ar = tid >> 2, ac = (tid & 3) << 2;
  int br = tid >> 4, bc = (tid & 15) << 2;
  float acc[4][4];
  #pragma unroll
  for (int i = 0; i < 4; i++)
    #pragma unroll
    for (int j = 0; j < 4; j++) acc[i][j] = 0.f;
  for (int k0 = 0; k0 < K; k0 += 16) {
    float4 av = *(const float4*)(A + (size_t)(row0 + ar) * K + k0 + ac);
    As[ac + 0][ar] = av.x; As[ac + 1][ar] = av.y; As[ac + 2][ar] = av.z; As[ac + 3][ar] = av.w;
    *(float4*)(&Bs[br][bc]) = *(const float4*)(B + (size_t)(k0 + br) * N + col0 + bc);
    __syncthreads();
    #pragma unroll
    for (int kk = 0; kk < 16; kk++) {
      float4 a = *(const float4*)(&As[kk][ty << 2]);
      float4 b = *(const float4*)(&Bs[kk][tx << 2]);
      acc[0][0] += a.x * b.x; acc[0][1] += a.x * b.y; acc[0][2] += a.x * b.z; acc[0][3] += a.x * b.w;
      acc[1][0] += a.y * b.x; acc[1][1] += a.y * b.y; acc[1][2] += a.y * b.z; acc[1][3] += a.y * b.w;
      acc[2][0] += a.z * b.x; acc[2][1] += a.z * b.y; acc[2][2] += a.z * b.z; acc[2][3] += a.z * b.w;
      acc[3][0] += a.w * b.x; acc[3][1] += a.w * b.y; acc[3][2] += a.w * b.z; acc[3][3] += a.w * b.w;
    }
    __syncthreads();
  }
  #pragma unroll
  for (int i = 0; i < 4; i++) {
    int row = row0 + (ty << 2) + i;
    #pragma unroll
    for (int j = 0; j < 4; j++) {
      int col = col0 + (tx << 2) + j;
      float bv = bias ? bias[col] : 0.f;
      C[(size_t)row * N + col] = acc[i][j] + bv;
    }
  }
}

// graph mean pool + build GRU input sequence [B,5,1024] = [agent_emb | graph_emb]
__global__ void k_pool(const float* __restrict__ x3, float* __restrict__ combined) {
  int b = blockIdx.x, tid = threadIdx.x;   // 256 threads
  float a0 = 0.f, a1 = 0.f;
  for (int n = 0; n < NP; n++) {
    const float* r = x3 + (size_t)(b * NP + n) * FF;
    a0 += r[tid]; a1 += r[tid + 256];
  }
  a0 *= (1.f / NP); a1 *= (1.f / NP);
  for (int t = 0; t < 5; t++) {
    float* cb = combined + (size_t)(b * 5 + t) * GRUIN;
    const float* ag = x3 + (size_t)(b * NP + t) * FF;
    cb[tid] = ag[tid];
    cb[tid + 256] = ag[tid + 256];
    cb[512 + tid] = a0;
    cb[768 + tid] = a1;
  }
}

// GRU: one block per batch element, 5 sequential steps. gi_all already has bih.
__global__ void k_gru(const float* __restrict__ gi_all, const float* __restrict__ h0,
                      const float* __restrict__ Whh, const float* __restrict__ bhh,
                      float* __restrict__ gru_out, float* __restrict__ hlast) {
  int b = blockIdx.x, tid = threadIdx.x;   // 384 threads
  __shared__ float hl[GRUH];
  __shared__ float ghb[384];
  if (tid < GRUH) hl[tid] = h0[b * GRUH + tid];
  for (int t = 0; t < 5; t++) {
    __syncthreads();
    float acc = bhh[tid];
    for (int k = 0; k < GRUH; k++) acc += hl[k] * Whh[k * 384 + tid];
    ghb[tid] = acc;
    __syncthreads();
    if (tid < GRUH) {
      const float* gi = gi_all + (size_t)(b * 5 + t) * 384;
      float r = 1.f / (1.f + expf(-(gi[tid] + ghb[tid])));
      float z = 1.f / (1.f + expf(-(gi[128 + tid] + ghb[128 + tid])));
      float nn = tanhf(gi[256 + tid] + r * ghb[256 + tid]);
      float hn = (1.f - z) * nn + z * hl[tid];
      gru_out[(size_t)(b * 5 + t) * GRUH + tid] = hn;
      hl[tid] = hn;
    }
  }
  __syncthreads();
  if (tid < GRUH) hlast[b * GRUH + tid] = hl[tid];
}

// fc1(relu) + fc2 + action_std, one block (64 thr) per (b,t) row
__global__ void k_fc(const float* __restrict__ gru_out, const float* __restrict__ fc1W,
                     const float* __restrict__ fc1b, const float* __restrict__ fc2W,
                     const float* __restrict__ fc2b, const float* __restrict__ log_std,
                     float* __restrict__ dout) {
  int row = blockIdx.x, tid = threadIdx.x;   // 64 threads
  __shared__ float gbuf[GRUH];
  __shared__ float f1[64];
  gbuf[tid] = gru_out[(size_t)row * GRUH + tid];
  gbuf[tid + 64] = gru_out[(size_t)row * GRUH + 64 + tid];
  __syncthreads();
  float acc = fc1b[tid];
  for (int k = 0; k < GRUH; k++) acc += gbuf[k] * fc1W[k * 64 + tid];
  f1[tid] = fmaxf(acc, 0.f);
  __syncthreads();
  if (tid < 3) {
    float o = fc2b[tid];
    for (int j = 0; j < 64; j++) o += f1[j] * fc2W[j * 3 + tid];
    dout[row * 3 + tid] = o;
    float ls = log_std[tid];
    ls = fminf(fmaxf(ls, -20.f), 2.f);
    dout[7680 + row * 3 + tid] = expf(ls);
  }
}

extern "C" void kernel_launch(void* const* d_in, const int* in_sizes, int n_in,
                              void* d_out, int out_size, void* d_ws, size_t ws_size,
                              hipStream_t stream) {
  const float* x      = (const float*)d_in[0];
  const int*   ei     = (const int*)d_in[1];
  const float* eattr  = (const float*)d_in[2];
  const float* hstate = (const float*)d_in[3];
  const float* W1  = (const float*)d_in[4];
  const float* as1 = (const float*)d_in[5];
  const float* ad1 = (const float*)d_in[6];
  const float* We1 = (const float*)d_in[7];
  const float* ae1 = (const float*)d_in[8];
  const float* b1  = (const float*)d_in[9];
  const float* W2  = (const float*)d_in[10];
  const float* as2 = (const float*)d_in[11];
  const float* ad2 = (const float*)d_in[12];
  const float* We2 = (const float*)d_in[13];
  const float* ae2 = (const float*)d_in[14];
  const float* b2  = (const float*)d_in[15];
  const float* W3  = (const float*)d_in[16];
  const float* as3 = (const float*)d_in[17];
  const float* ad3 = (const float*)d_in[18];
  const float* We3 = (const float*)d_in[19];
  const float* ae3 = (const float*)d_in[20];
  const float* b3  = (const float*)d_in[21];
  const float* Wih = (const float*)d_in[22];
  const float* Whh = (const float*)d_in[23];
  const float* bih = (const float*)d_in[24];
  const float* bhh = (const float*)d_in[25];
  const float* fc1W = (const float*)d_in[26];
  const float* fc1b = (const float*)d_in[27];
  const float* fc2W = (const float*)d_in[28];
  const float* fc2b = (const float*)d_in[29];
  const float* lstd = (const float*)d_in[30];

  float* ws = (float*)d_ws;
  float* xbuf  = ws;                       // 13,107,200 floats
  float* hbuf  = xbuf + 13107200;          // 13,107,200
  float* ssrc  = hbuf + 13107200;          // 204,800
  float* sdst  = ssrc + 204800;            // 204,800
  float* lattr = sdst + 204800;            // 25,600
  float* eea   = lattr + 25600;            // 204,800
  float* wdot  = eea + 204800;             // 32
  int*   rowp  = (int*)(wdot + 32);        // 32,768 ints
  int*   esrc  = rowp + 32768;             // 204,800 ints
  // overlays into xbuf (free after layer 3; x3 lives in hbuf)
  float* combined = xbuf;                  // 2,621,440
  float* gi_all   = xbuf + 2621440;        // 983,040
  float* gru_out  = gi_all + 983040;       // 327,680
  float* dout = (float*)d_out;

  k_wedot<<<3, 512, 0, stream>>>(We1, ae1, We2, ae2, We3, ae3, wdot);
  k_csr<<<BB, 256, 0, stream>>>(ei, eattr, rowp, esrc, eea, lattr);

  // layer 1: h1 in hbuf, x1 in hbuf (in-place gat)
  k_conv1<<<51200, 256, 0, stream>>>(x, W1, hbuf);
  k_dots<<<51200, 256, 0, stream>>>(hbuf, as1, ad1, ssrc, sdst);
  k_gat<<<dim3(BB, HH), 256, 0, stream>>>(hbuf, hbuf, ssrc, sdst, rowp, esrc, eea, lattr, wdot, b1, 0, 0);

  // layer 2: h2 = x1@W2 -> xbuf, x2 in xbuf
  k_sgemm<<<dim3(8, 400), 256, 0, stream>>>(hbuf, W2, nullptr, xbuf, NN, FF, FF);
  k_dots<<<51200, 256, 0, stream>>>(xbuf, as2, ad2, ssrc, sdst);
  k_gat<<<dim3(BB, HH), 256, 0, stream>>>(xbuf, xbuf, ssrc, sdst, rowp, esrc, eea, lattr, wdot, b2, 1, 1);

  // layer 3: h3 = x2@W3 -> hbuf, x3 in hbuf
  k_sgemm<<<dim3(8, 400), 256, 0, stream>>>(xbuf, W3, nullptr, hbuf, NN, FF, FF);
  k_dots<<<51200, 256, 0, stream>>>(hbuf, as3, ad3, ssrc, sdst);
  k_gat<<<dim3(BB, HH), 256, 0, stream>>>(hbuf, hbuf, ssrc, sdst, rowp, esrc, eea, lattr, wdot, b3, 2, 1);

  // pool + GRU input GEMM (gi includes bih)
  k_pool<<<BB, 256, 0, stream>>>(hbuf, combined);
  k_sgemm<<<dim3(6, 40), 256, 0, stream>>>(combined, Wih, bih, gi_all, 2560, 384, 1024);

  // GRU scan + heads
  k_gru<<<BB, 384, 0, stream>>>(gi_all, hstate, Whh, bhh, gru_out, dout + 15360);
  k_fc<<<2560, 64, 0, stream>>>(gru_out, fc1W, fc1b, fc2W, fc2b, lstd, dout);
}

// Round 2
// 624.094 us; speedup vs baseline: 1.5331x; 1.5331x over previous
//
#include <hip/hip_runtime.h>
#include <math.h>

#define NN 25600      // total nodes
#define BB 512        // graphs
#define NP 50         // nodes per graph
#define EPG 400       // edges per graph
#define EE 204800     // total edges
#define HH 8
#define CC 64
#define FF 512
#define GRUH 128
#define GRUIN 1024

typedef unsigned short ushort_t;
typedef __attribute__((ext_vector_type(8))) short bf16x8;
typedef __attribute__((ext_vector_type(4))) float f32x4;

__device__ __forceinline__ float wave_reduce_sum(float v) {
  #pragma unroll
  for (int m = 32; m >= 1; m >>= 1) v += __shfl_xor(v, m, 64);
  return v;
}

__device__ __forceinline__ ushort_t f2bf(float x) {
  union { float f; unsigned int u; } v; v.f = x;
  unsigned int r = v.u + 0x7fffu + ((v.u >> 16) & 1u);   // RNE
  return (ushort_t)(r >> 16);
}

__device__ __forceinline__ void gload_lds16(const ushort_t* g, ushort_t* l) {
  __builtin_amdgcn_global_load_lds(
      (const __attribute__((address_space(1))) void*)g,
      (__attribute__((address_space(3))) void*)l, 16, 0, 0);
}

// we_dot[l*8+h] = sum_c We_l[h*64+c] * ae_l[h*64+c]
__global__ void k_wedot(const float* __restrict__ We1, const float* __restrict__ ae1,
                        const float* __restrict__ We2, const float* __restrict__ ae2,
                        const float* __restrict__ We3, const float* __restrict__ ae3,
                        float* __restrict__ wdot) {
  const float* We = blockIdx.x == 0 ? We1 : (blockIdx.x == 1 ? We2 : We3);
  const float* ae = blockIdx.x == 0 ? ae1 : (blockIdx.x == 1 ? ae2 : ae3);
  int head = threadIdx.x >> 6, lane = threadIdx.x & 63;
  float v = We[head * 64 + lane] * ae[head * 64 + lane];
  v = wave_reduce_sum(v);
  if (lane == 0) wdot[blockIdx.x * 8 + head] = v;
}

// Per-graph CSR by dst (local ids), plus loop_attr = mean incoming edge_attr.
__global__ void k_csr(const int* __restrict__ ei, const float* __restrict__ eattr,
                      int* __restrict__ rowp, int* __restrict__ esrc,
                      float* __restrict__ eea, float* __restrict__ lattr) {
  int g = blockIdx.x, tid = threadIdx.x;
  __shared__ int cnt[NP];
  __shared__ float esum[NP];
  __shared__ int rp[NP + 1];
  __shared__ int cur[NP];
  if (tid < NP) { cnt[tid] = 0; esum[tid] = 0.f; }
  __syncthreads();
  for (int e = tid; e < EPG; e += blockDim.x) {
    int ge = g * EPG + e;
    int dl = ei[EE + ge] - g * NP;
    atomicAdd(&cnt[dl], 1);
    atomicAdd(&esum[dl], eattr[ge]);
  }
  __syncthreads();
  if (tid == 0) {
    int s = 0;
    for (int i = 0; i < NP; i++) { rp[i] = s; cur[i] = s; s += cnt[i]; }
    rp[NP] = s;
  }
  __syncthreads();
  if (tid <= NP) rowp[g * 64 + tid] = rp[tid];
  if (tid < NP) lattr[g * NP + tid] = esum[tid] / (float)max(cnt[tid], 1);
  for (int e = tid; e < EPG; e += blockDim.x) {
    int ge = g * EPG + e;
    int sl = ei[ge] - g * NP;
    int dl = ei[EE + ge] - g * NP;
    int pos = atomicAdd(&cur[dl], 1);
    esrc[g * EPG + pos] = sl;
    eea[g * EPG + pos] = eattr[ge];
  }
}

// transpose + fp32->bf16: Wt[n][k] = bf16(W[k][n]); K,N multiples of 32
__global__ __launch_bounds__(256) void k_cvt_t(const float* __restrict__ W,
                                               ushort_t* __restrict__ Wt,
                                               int K, int N) {
  __shared__ float t[32][33];
  int n0 = blockIdx.x * 32, k0 = blockIdx.y * 32;
  int tx = threadIdx.x & 31, ty = threadIdx.x >> 5;   // ty 0..7
  #pragma unroll
  for (int i = 0; i < 4; i++)
    t[ty + i * 8][tx] = W[(size_t)(k0 + ty + i * 8) * N + n0 + tx];
  __syncthreads();
  #pragma unroll
  for (int i = 0; i < 4; i++)
    Wt[(size_t)(n0 + ty + i * 8) * K + k0 + tx] = f2bf(t[tx][ty + i * 8]);
}

// h1 = x @ W1  ([N,4]@[4,512])
__global__ void k_conv1(const float* __restrict__ x, const float* __restrict__ W1,
                        float* __restrict__ h) {
  int i = blockIdx.x * 256 + threadIdx.x;
  int n = i >> 9, f = i & 511;
  const float* xr = x + n * 4;
  h[i] = xr[0] * W1[f] + xr[1] * W1[512 + f] + xr[2] * W1[1024 + f] + xr[3] * W1[1536 + f];
}

// s_src[n,h], s_dst[n,h]: one wave per (n,h)
__global__ void k_dots(const float* __restrict__ h, const float* __restrict__ a_src,
                       const float* __restrict__ a_dst, float* __restrict__ ssrc,
                       float* __restrict__ sdst) {
  int wid = blockIdx.x * 4 + (threadIdx.x >> 6);
  int lane = threadIdx.x & 63;
  int n = wid >> 3, hd = wid & 7;
  float v = h[(size_t)n * FF + hd * 64 + lane];
  float s1 = wave_reduce_sum(v * a_src[hd * 64 + lane]);
  float s2 = wave_reduce_sum(v * a_dst[hd * 64 + lane]);
  if (lane == 0) { ssrc[n * 8 + hd] = s1; sdst[n * 8 + hd] = s2; }
}

// One block per (graph, head): softmax attention -> dense 50x50 A -> A @ h_tile.
// If xout_bf != null, write bf16 output (fp32 xout untouched); else write fp32
// (in-place safe: block reads its own rows/head-slice to LDS before writing).
__global__ __launch_bounds__(256) void k_gat(
    const float* __restrict__ hin, float* __restrict__ xout,
    ushort_t* __restrict__ xout_bf,
    const float* __restrict__ ssrc, const float* __restrict__ sdst,
    const int* __restrict__ rowp, const int* __restrict__ esrcg,
    const float* __restrict__ eeag, const float* __restrict__ lattr,
    const float* __restrict__ wdot_all, const float* __restrict__ bias,
    int layer, int self_loops) {
  int g = blockIdx.x, hd = blockIdx.y, tid = threadIdx.x;
  __shared__ float h_tile[NP * CC];
  __shared__ float Amat[NP * NP];
  __shared__ float ssl[NP], sdl[NP], lat[NP];
  __shared__ float albuf[EPG];
  __shared__ int rp[NP + 1];
  __shared__ int es[EPG];
  __shared__ float ea[EPG];

  float wdot = wdot_all[layer * 8 + hd];
  for (int i = tid; i < NP * CC; i += 256) {
    int s = i >> 6, c = i & 63;
    h_tile[i] = hin[(size_t)(g * NP + s) * FF + hd * 64 + c];
  }
  for (int i = tid; i < EPG; i += 256) { es[i] = esrcg[g * EPG + i]; ea[i] = eeag[g * EPG + i]; }
  if (tid <= NP) rp[tid] = rowp[g * 64 + tid];
  if (tid < NP) {
    ssl[tid] = ssrc[(g * NP + tid) * 8 + hd];
    sdl[tid] = sdst[(g * NP + tid) * 8 + hd];
    lat[tid] = lattr[g * NP + tid];
  }
  for (int i = tid; i < NP * NP; i += 256) Amat[i] = 0.f;
  __syncthreads();

  if (tid < NP) {
    int d = tid;
    int e0 = rp[d], e1 = rp[d + 1];
    float sd = sdl[d];
    float m = -1e30f;
    for (int e = e0; e < e1; e++) {
      float al = ssl[es[e]] + sd + ea[e] * wdot;
      al = al > 0.f ? al : 0.2f * al;   // leaky_relu 0.2
      albuf[e] = al;
      m = fmaxf(m, al);
    }
    float al_loop = 0.f;
    if (self_loops) {
      al_loop = ssl[d] + sd + lat[d] * wdot;
      al_loop = al_loop > 0.f ? al_loop : 0.2f * al_loop;
      m = fmaxf(m, al_loop);
    }
    if (e1 > e0 || self_loops) {
      float denom = 0.f;
      for (int e = e0; e < e1; e++) { float p = expf(albuf[e] - m); albuf[e] = p; denom += p; }
      float ploop = 0.f;
      if (self_loops) { ploop = expf(al_loop - m); denom += ploop; }
      float inv = 1.f / (denom + 1e-16f);
      for (int e = e0; e < e1; e++) Amat[d * NP + es[e]] += albuf[e] * inv;
      if (self_loops) Amat[d * NP + d] += ploop * inv;
    }
  }
  __syncthreads();

  // out[d][c] = sum_s A[d][s] * h_tile[s][c]; thread: c = tid&63, d in {dg, dg+4, ...}
  int c = tid & 63, dg = tid >> 6;
  float acc[13];
  #pragma unroll
  for (int j = 0; j < 13; j++) acc[j] = 0.f;
  for (int s = 0; s < NP; s++) {
    float hv = h_tile[s * 64 + c];
    #pragma unroll
    for (int j = 0; j < 13; j++) {
      int d = dg + j * 4;
      if (d < NP) acc[j] += Amat[d * NP + s] * hv;
    }
  }
  float bb = bias[hd * 64 + c];
  if (xout_bf) {
    #pragma unroll
    for (int j = 0; j < 13; j++) {
      int d = dg + j * 4;
      if (d < NP) xout_bf[(size_t)(g * NP + d) * FF + hd * 64 + c] = f2bf(fmaxf(acc[j] + bb, 0.f));
    }
  } else {
    #pragma unroll
    for (int j = 0; j < 13; j++) {
      int d = dg + j * 4;
      if (d < NP) xout[(size_t)(g * NP + d) * FF + hd * 64 + c] = fmaxf(acc[j] + bb, 0.f);
    }
  }
}

// bf16 MFMA GEMM: C[M][N] fp32 = A[M][K]bf16 @ Bt[N][K]bf16^T (+bias).
// 128x128 tile, 4 waves (each 64x64 = 4x4 of 16x16x32 MFMA), BK=32,
// global_load_lds width-16 staging (m97 structure). M%128==0, N%128==0, K%32==0.
__global__ __launch_bounds__(256) void k_bgemm(
    const ushort_t* __restrict__ A, const ushort_t* __restrict__ Bt,
    const float* __restrict__ bias, float* __restrict__ C,
    int M, int N, int K) {
  __shared__ ushort_t As[128 * 32];   // [row][k], 64 B per row
  __shared__ ushort_t Bs[128 * 32];   // [n][k]
  int tid = threadIdx.x;
  int w = tid >> 6, l = tid & 63;
  int row0 = blockIdx.y * 128, col0 = blockIdx.x * 128;
  int wr = w >> 1, wc = w & 1;

  f32x4 acc[4][4];
  #pragma unroll
  for (int i = 0; i < 4; i++)
    #pragma unroll
    for (int j = 0; j < 4; j++) acc[i][j] = (f32x4){0.f, 0.f, 0.f, 0.f};

  // staging: wave w covers tile rows [w*32, w*32+32); inst j adds 16 rows.
  int srow = w * 32 + (l >> 2);
  int skcol = (l & 3) * 8;
  const ushort_t* Ag = A + (size_t)(row0 + srow) * K + skcol;
  const ushort_t* Bg = Bt + (size_t)(col0 + srow) * K + skcol;
  ushort_t* AsW = &As[w * 1024];      // wave-uniform LDS base (bytes w*2048)
  ushort_t* BsW = &Bs[w * 1024];

  int m_l = l & 15, kq = (l >> 4) * 8;
  const ushort_t* ArdA = &As[(wr * 64 + m_l) * 32 + kq];
  const ushort_t* BrdB = &Bs[(wc * 64 + m_l) * 32 + kq];

  for (int k0 = 0; k0 < K; k0 += 32) {
    gload_lds16(Ag + k0, AsW);
    gload_lds16(Ag + (size_t)16 * K + k0, AsW + 512);
    gload_lds16(Bg + k0, BsW);
    gload_lds16(Bg + (size_t)16 * K + k0, BsW + 512);
    __syncthreads();
    bf16x8 af[4], bfr[4];
    #pragma unroll
    for (int t = 0; t < 4; t++) {
      af[t]  = *(const bf16x8*)(ArdA + t * 16 * 32);
      bfr[t] = *(const bf16x8*)(BrdB + t * 16 * 32);
    }
    #pragma unroll
    for (int mt = 0; mt < 4; mt++)
      #pragma unroll
      for (int nt = 0; nt < 4; nt++)
        acc[mt][nt] = __builtin_amdgcn_mfma_f32_16x16x32_bf16(af[mt], bfr[nt], acc[mt][nt], 0, 0, 0);
    __syncthreads();
  }

  // C/D layout: col = lane&15, row = (lane>>4)*4 + reg   [m89/m91 verified]
  int cl = l & 15, rq = (l >> 4) * 4;
  #pragma unroll
  for (int mt = 0; mt < 4; mt++) {
    #pragma unroll
    for (int nt = 0; nt < 4; nt++) {
      int col = col0 + wc * 64 + nt * 16 + cl;
      float bv = bias ? bias[col] : 0.f;
      #pragma unroll
      for (int r = 0; r < 4; r++) {
        int row = row0 + wr * 64 + mt * 16 + rq + r;
        C[(size_t)row * N + col] = acc[mt][nt][r] + bv;
      }
    }
  }
}

// graph mean pool + GRU input sequence [B,5,1024]=[agent|graph], bf16 out
__global__ void k_pool(const float* __restrict__ x3, ushort_t* __restrict__ combined) {
  int b = blockIdx.x, tid = threadIdx.x;   // 256 threads
  float a0 = 0.f, a1 = 0.f;
  for (int n = 0; n < NP; n++) {
    const float* r = x3 + (size_t)(b * NP + n) * FF;
    a0 += r[tid]; a1 += r[tid + 256];
  }
  a0 *= (1.f / NP); a1 *= (1.f / NP);
  ushort_t b0 = f2bf(a0), b1v = f2bf(a1);
  for (int t = 0; t < 5; t++) {
    ushort_t* cb = combined + (size_t)(b * 5 + t) * GRUIN;
    const float* ag = x3 + (size_t)(b * NP + t) * FF;
    cb[tid] = f2bf(ag[tid]);
    cb[tid + 256] = f2bf(ag[tid + 256]);
    cb[512 + tid] = b0;
    cb[768 + tid] = b1v;
  }
}

// GRU: one block per batch element, 5 sequential steps. gi_all already has bih.
__global__ void k_gru(const float* __restrict__ gi_all, const float* __restrict__ h0,
                      const float* __restrict__ Whh, const float* __restrict__ bhh,
                      float* __restrict__ gru_out, float* __restrict__ hlast) {
  int b = blockIdx.x, tid = threadIdx.x;   // 384 threads
  __shared__ float hl[GRUH];
  __shared__ float ghb[384];
  if (tid < GRUH) hl[tid] = h0[b * GRUH + tid];
  for (int t = 0; t < 5; t++) {
    __syncthreads();
    float acc = bhh[tid];
    for (int k = 0; k < GRUH; k++) acc += hl[k] * Whh[k * 384 + tid];
    ghb[tid] = acc;
    __syncthreads();
    if (tid < GRUH) {
      const float* gi = gi_all + (size_t)(b * 5 + t) * 384;
      float r = 1.f / (1.f + expf(-(gi[tid] + ghb[tid])));
      float z = 1.f / (1.f + expf(-(gi[128 + tid] + ghb[128 + tid])));
      float nn = tanhf(gi[256 + tid] + r * ghb[256 + tid]);
      float hn = (1.f - z) * nn + z * hl[tid];
      gru_out[(size_t)(b * 5 + t) * GRUH + tid] = hn;
      hl[tid] = hn;
    }
  }
  __syncthreads();
  if (tid < GRUH) hlast[b * GRUH + tid] = hl[tid];
}

// fc1(relu) + fc2 + action_std, one block (64 thr) per (b,t) row
__global__ void k_fc(const float* __restrict__ gru_out, const float* __restrict__ fc1W,
                     const float* __restrict__ fc1b, const float* __restrict__ fc2W,
                     const float* __restrict__ fc2b, const float* __restrict__ log_std,
                     float* __restrict__ dout) {
  int row = blockIdx.x, tid = threadIdx.x;   // 64 threads
  __shared__ float gbuf[GRUH];
  __shared__ float f1[64];
  gbuf[tid] = gru_out[(size_t)row * GRUH + tid];
  gbuf[tid + 64] = gru_out[(size_t)row * GRUH + 64 + tid];
  __syncthreads();
  float acc = fc1b[tid];
  for (int k = 0; k < GRUH; k++) acc += gbuf[k] * fc1W[k * 64 + tid];
  f1[tid] = fmaxf(acc, 0.f);
  __syncthreads();
  if (tid < 3) {
    float o = fc2b[tid];
    for (int j = 0; j < 64; j++) o += f1[j] * fc2W[j * 3 + tid];
    dout[row * 3 + tid] = o;
    float ls = log_std[tid];
    ls = fminf(fmaxf(ls, -20.f), 2.f);
    dout[7680 + row * 3 + tid] = expf(ls);
  }
}

extern "C" void kernel_launch(void* const* d_in, const int* in_sizes, int n_in,
                              void* d_out, int out_size, void* d_ws, size_t ws_size,
                              hipStream_t stream) {
  const float* x      = (const float*)d_in[0];
  const int*   ei     = (const int*)d_in[1];
  const float* eattr  = (const float*)d_in[2];
  const float* hstate = (const float*)d_in[3];
  const float* W1  = (const float*)d_in[4];
  const float* as1 = (const float*)d_in[5];
  const float* ad1 = (const float*)d_in[6];
  const float* We1 = (const float*)d_in[7];
  const float* ae1 = (const float*)d_in[8];
  const float* b1  = (const float*)d_in[9];
  const float* W2  = (const float*)d_in[10];
  const float* as2 = (const float*)d_in[11];
  const float* ad2 = (const float*)d_in[12];
  const float* We2 = (const float*)d_in[13];
  const float* ae2 = (const float*)d_in[14];
  const float* b2  = (const float*)d_in[15];
  const float* W3  = (const float*)d_in[16];
  const float* as3 = (const float*)d_in[17];
  const float* ad3 = (const float*)d_in[18];
  const float* We3 = (const float*)d_in[19];
  const float* ae3 = (const float*)d_in[20];
  const float* b3  = (const float*)d_in[21];
  const float* Wih = (const float*)d_in[22];
  const float* Whh = (const float*)d_in[23];
  const float* bih = (const float*)d_in[24];
  const float* bhh = (const float*)d_in[25];
  const float* fc1W = (const float*)d_in[26];
  const float* fc1b = (const float*)d_in[27];
  const float* fc2W = (const float*)d_in[28];
  const float* fc2b = (const float*)d_in[29];
  const float* lstd = (const float*)d_in[30];

  float* ws = (float*)d_ws;
  float*   hbuf = ws;                                  // 13,107,200 floats
  ushort_t* xbf = (ushort_t*)(ws + 13107200);          // 13,107,200 ushorts
  float* p = ws + 13107200 + 6553600;
  float* ssrc  = p;           p += 204800;
  float* sdst  = p;           p += 204800;
  float* lattr = p;           p += 25600;
  float* eea   = p;           p += 204800;
  float* wdot  = p;           p += 32;
  int*   rowp  = (int*)p;     p += 32768;
  int*   esrc  = (int*)p;     p += 204800;
  ushort_t* w2t  = (ushort_t*)p;  p += 131072;   // 262144 ushorts
  ushort_t* w3t  = (ushort_t*)p;  p += 131072;
  ushort_t* wiht = (ushort_t*)p;  p += 196608;   // 393216 ushorts
  ushort_t* cbf  = (ushort_t*)p;  p += 1310720;  // 2,621,440 ushorts
  float* gi_all  = p;         p += 983040;       // [2560][384]
  float* gru_out = p;         p += 327680;
  float* dout = (float*)d_out;

  k_wedot<<<3, 512, 0, stream>>>(We1, ae1, We2, ae2, We3, ae3, wdot);
  k_csr<<<BB, 256, 0, stream>>>(ei, eattr, rowp, esrc, eea, lattr);
  k_cvt_t<<<dim3(16, 16), 256, 0, stream>>>(W2, w2t, FF, FF);      // w2t[n][k]
  k_cvt_t<<<dim3(16, 16), 256, 0, stream>>>(W3, w3t, FF, FF);
  k_cvt_t<<<dim3(12, 32), 256, 0, stream>>>(Wih, wiht, GRUIN, 384);

  // layer 1: h1 -> hbuf; gat1 -> xbf (bf16)
  k_conv1<<<51200, 256, 0, stream>>>(x, W1, hbuf);
  k_dots<<<51200, 256, 0, stream>>>(hbuf, as1, ad1, ssrc, sdst);
  k_gat<<<dim3(BB, HH), 256, 0, stream>>>(hbuf, nullptr, xbf, ssrc, sdst, rowp, esrc, eea, lattr, wdot, b1, 0, 0);

  // layer 2: h2 = x1_bf @ W2t -> hbuf (fp32); gat2 -> xbf (bf16)
  k_bgemm<<<dim3(4, 200), 256, 0, stream>>>(xbf, w2t, nullptr, hbuf, NN, FF, FF);
  k_dots<<<51200, 256, 0, stream>>>(hbuf, as2, ad2, ssrc, sdst);
  k_gat<<<dim3(BB, HH), 256, 0, stream>>>(hbuf, nullptr, xbf, ssrc, sdst, rowp, esrc, eea, lattr, wdot, b2, 1, 1);

  // layer 3: h3 = x2_bf @ W3t -> hbuf; gat3 in-place fp32 (x3 in hbuf)
  k_bgemm<<<dim3(4, 200), 256, 0, stream>>>(xbf, w3t, nullptr, hbuf, NN, FF, FF);
  k_dots<<<51200, 256, 0, stream>>>(hbuf, as3, ad3, ssrc, sdst);
  k_gat<<<dim3(BB, HH), 256, 0, stream>>>(hbuf, hbuf, nullptr, ssrc, sdst, rowp, esrc, eea, lattr, wdot, b3, 2, 1);

  // pool (bf16 combined) + GRU input GEMM (adds bih)
  k_pool<<<BB, 256, 0, stream>>>(hbuf, cbf);
  k_bgemm<<<dim3(3, 20), 256, 0, stream>>>(cbf, wiht, bih, gi_all, 2560, 384, GRUIN);

  // GRU scan + heads
  k_gru<<<BB, 384, 0, stream>>>(gi_all, hstate, Whh, bhh, gru_out, dout + 15360);
  k_fc<<<2560, 64, 0, stream>>>(gru_out, fc1W, fc1b, fc2W, fc2b, lstd, dout);
}

// Round 3
// 432.388 us; speedup vs baseline: 2.2128x; 1.4434x over previous
//
#include <hip/hip_runtime.h>
#include <math.h>

#define NN 25600      // total nodes
#define BB 512        // graphs
#define NP 50         // nodes per graph
#define EPG 400       // edges per graph
#define EE 204800     // total edges
#define HH 8
#define CC 64
#define FF 512
#define GRUH 128
#define GRUIN 1024

typedef unsigned short ushort_t;
typedef __attribute__((ext_vector_type(8))) short bf16x8;
typedef __attribute__((ext_vector_type(4))) float f32x4;

__device__ __forceinline__ float wave_reduce_sum(float v) {
  #pragma unroll
  for (int m = 32; m >= 1; m >>= 1) v += __shfl_xor(v, m, 64);
  return v;
}

__device__ __forceinline__ ushort_t f2bf(float x) {
  union { float f; unsigned int u; } v; v.f = x;
  unsigned int r = v.u + 0x7fffu + ((v.u >> 16) & 1u);   // RNE
  return (ushort_t)(r >> 16);
}

__device__ __forceinline__ float bf2f(ushort_t u) {
  union { unsigned int u; float f; } v; v.u = ((unsigned int)u) << 16;
  return v.f;
}

__device__ __forceinline__ void gload_lds16(const ushort_t* g, ushort_t* l) {
  __builtin_amdgcn_global_load_lds(
      (const __attribute__((address_space(1))) void*)g,
      (__attribute__((address_space(3))) void*)l, 16, 0, 0);
}

// we_dot[l*8+h] = sum_c We_l[h*64+c] * ae_l[h*64+c]
__global__ void k_wedot(const float* __restrict__ We1, const float* __restrict__ ae1,
                        const float* __restrict__ We2, const float* __restrict__ ae2,
                        const float* __restrict__ We3, const float* __restrict__ ae3,
                        float* __restrict__ wdot) {
  const float* We = blockIdx.x == 0 ? We1 : (blockIdx.x == 1 ? We2 : We3);
  const float* ae = blockIdx.x == 0 ? ae1 : (blockIdx.x == 1 ? ae2 : ae3);
  int head = threadIdx.x >> 6, lane = threadIdx.x & 63;
  float v = We[head * 64 + lane] * ae[head * 64 + lane];
  v = wave_reduce_sum(v);
  if (lane == 0) wdot[blockIdx.x * 8 + head] = v;
}

// Per-graph CSR by dst (local ids), plus loop_attr = mean incoming edge_attr.
__global__ void k_csr(const int* __restrict__ ei, const float* __restrict__ eattr,
                      int* __restrict__ rowp, int* __restrict__ esrc,
                      float* __restrict__ eea, float* __restrict__ lattr) {
  int g = blockIdx.x, tid = threadIdx.x;
  __shared__ int cnt[NP];
  __shared__ float esum[NP];
  __shared__ int rp[NP + 1];
  __shared__ int cur[NP];
  if (tid < NP) { cnt[tid] = 0; esum[tid] = 0.f; }
  __syncthreads();
  for (int e = tid; e < EPG; e += blockDim.x) {
    int ge = g * EPG + e;
    int dl = ei[EE + ge] - g * NP;
    atomicAdd(&cnt[dl], 1);
    atomicAdd(&esum[dl], eattr[ge]);
  }
  __syncthreads();
  if (tid == 0) {
    int s = 0;
    for (int i = 0; i < NP; i++) { rp[i] = s; cur[i] = s; s += cnt[i]; }
    rp[NP] = s;
  }
  __syncthreads();
  if (tid <= NP) rowp[g * 64 + tid] = rp[tid];
  if (tid < NP) lattr[g * NP + tid] = esum[tid] / (float)max(cnt[tid], 1);
  for (int e = tid; e < EPG; e += blockDim.x) {
    int ge = g * EPG + e;
    int sl = ei[ge] - g * NP;
    int dl = ei[EE + ge] - g * NP;
    int pos = atomicAdd(&cur[dl], 1);
    esrc[g * EPG + pos] = sl;
    eea[g * EPG + pos] = eattr[ge];
  }
}

// transpose + fp32->bf16: Wt[n][k] = bf16(W[k][n]); K,N multiples of 32
__global__ __launch_bounds__(256) void k_cvt_t(const float* __restrict__ W,
                                               ushort_t* __restrict__ Wt,
                                               int K, int N) {
  __shared__ float t[32][33];
  int n0 = blockIdx.x * 32, k0 = blockIdx.y * 32;
  int tx = threadIdx.x & 31, ty = threadIdx.x >> 5;   // ty 0..7
  #pragma unroll
  for (int i = 0; i < 4; i++)
    t[ty + i * 8][tx] = W[(size_t)(k0 + ty + i * 8) * N + n0 + tx];
  __syncthreads();
  #pragma unroll
  for (int i = 0; i < 4; i++)
    Wt[(size_t)(n0 + ty + i * 8) * K + k0 + tx] = f2bf(t[tx][ty + i * 8]);
}

// Fused GAT layer (one block per graph,head):
//   [optional conv1: h = x@W1]  +  attention dots (wave-reduce)  +
//   softmax over CSR  ->  bf16 A-tile (64x72)  ->  MFMA A@h  ->  relu+bias -> bf16 out.
__global__ __launch_bounds__(256) void k_gatm(
    const float* __restrict__ hin,       // fp32 [N][512] (layers 2,3)
    const float* __restrict__ xin,       // raw x [N][4] (layer 1) or null
    const float* __restrict__ W1,        // [4][512] (layer 1) or null
    ushort_t* __restrict__ xout,         // bf16 [N][512]
    const float* __restrict__ a_src, const float* __restrict__ a_dst,  // [8*64]
    const int* __restrict__ rowp, const int* __restrict__ esrcg,
    const float* __restrict__ eeag, const float* __restrict__ lattr,
    const float* __restrict__ wdot_all, const float* __restrict__ bias,
    int layer, int self_loops) {
  int g = blockIdx.x, hd = blockIdx.y, tid = threadIdx.x;
  int w = tid >> 6, lane = tid & 63;

  __shared__ __align__(16) ushort_t ht[64 * 72];   // ht[c][s] bf16, stride 72
  __shared__ __align__(16) ushort_t Am[64 * 72];   // Am[d][s] bf16, stride 72
  __shared__ float ssl[64], sdl[64], lat[64];
  __shared__ float albuf[EPG];
  __shared__ float eaS[EPG];
  __shared__ int esS[EPG];
  __shared__ int rp[64];

  // zero A-tile and h-tile (padding rows/cols must be 0, not garbage/NaN)
  unsigned int* z1 = (unsigned int*)ht;
  unsigned int* z2 = (unsigned int*)Am;
  for (int i = tid; i < 64 * 72 / 2; i += 256) { z1[i] = 0u; z2[i] = 0u; }

  float asr = a_src[hd * 64 + lane], ads = a_dst[hd * 64 + lane];
  float wdot = wdot_all[layer * 8 + hd];
  float w1c0 = 0.f, w1c1 = 0.f, w1c2 = 0.f, w1c3 = 0.f;
  if (W1) {
    w1c0 = W1[hd * 64 + lane];        w1c1 = W1[512 + hd * 64 + lane];
    w1c2 = W1[1024 + hd * 64 + lane]; w1c3 = W1[1536 + hd * 64 + lane];
  }
  for (int i = tid; i < EPG; i += 256) { esS[i] = esrcg[g * EPG + i]; eaS[i] = eeag[g * EPG + i]; }
  if (tid <= NP) rp[tid] = rowp[g * 64 + tid];
  if (tid < NP) lat[tid] = lattr[g * NP + tid];
  __syncthreads();

  // stage h (transposed, bf16) + attention dots; wave w handles s = w, w+4, ...
  for (int i = 0; i < 13; i++) {
    int s = w + 4 * i;
    if (s < NP) {
      float hv;
      if (W1) {
        const float4 xv = *(const float4*)(xin + (size_t)(g * NP + s) * 4);
        hv = xv.x * w1c0 + xv.y * w1c1 + xv.z * w1c2 + xv.w * w1c3;
      } else {
        hv = hin[(size_t)(g * NP + s) * FF + hd * 64 + lane];
      }
      ht[lane * 72 + s] = f2bf(hv);
      float s1 = wave_reduce_sum(hv * asr);
      float s2 = wave_reduce_sum(hv * ads);
      if (lane == 0) { ssl[s] = s1; sdl[s] = s2; }
    }
  }
  __syncthreads();

  // per-dst softmax -> bf16 alpha row (RMW accumulate handles duplicate edges)
  if (tid < NP) {
    int d = tid;
    int e0 = rp[d], e1 = rp[d + 1];
    float sd = sdl[d];
    float m = -1e30f;
    for (int e = e0; e < e1; e++) {
      float al = ssl[esS[e]] + sd + eaS[e] * wdot;
      al = al > 0.f ? al : 0.2f * al;   // leaky_relu 0.2
      albuf[e] = al;
      m = fmaxf(m, al);
    }
    float al_loop = 0.f;
    if (self_loops) {
      al_loop = ssl[d] + sd + lat[d] * wdot;
      al_loop = al_loop > 0.f ? al_loop : 0.2f * al_loop;
      m = fmaxf(m, al_loop);
    }
    if (e1 > e0 || self_loops) {
      float denom = 0.f;
      for (int e = e0; e < e1; e++) { float p = expf(albuf[e] - m); albuf[e] = p; denom += p; }
      float ploop = 0.f;
      if (self_loops) { ploop = expf(al_loop - m); denom += ploop; }
      float inv = 1.f / (denom + 1e-16f);
      for (int e = e0; e < e1; e++) {
        int s = esS[e];
        float prev = bf2f(Am[d * 72 + s]);
        Am[d * 72 + s] = f2bf(prev + albuf[e] * inv);
      }
      if (self_loops) {
        float prev = bf2f(Am[d * 72 + d]);
        Am[d * 72 + d] = f2bf(prev + ploop * inv);
      }
    }
  }
  __syncthreads();

  // MFMA: out[d][c] = sum_s Am[d][s] * h[s][c]; wave w owns d-rows [w*16, w*16+16)
  int m_l = lane & 15, kq = lane >> 4;
  const ushort_t* Ard = &Am[(w * 16 + m_l) * 72 + kq * 8];
  f32x4 acc[4];
  #pragma unroll
  for (int ct = 0; ct < 4; ct++) acc[ct] = (f32x4){0.f, 0.f, 0.f, 0.f};
  #pragma unroll
  for (int ks = 0; ks < 2; ks++) {
    bf16x8 a = *(const bf16x8*)(Ard + ks * 32);
    #pragma unroll
    for (int ct = 0; ct < 4; ct++) {
      bf16x8 b = *(const bf16x8*)(&ht[(ct * 16 + m_l) * 72 + kq * 8 + ks * 32]);
      acc[ct] = __builtin_amdgcn_mfma_f32_16x16x32_bf16(a, b, acc[ct], 0, 0, 0);
    }
  }

  // epilogue: C/D layout col=lane&15, row=(lane>>4)*4+reg
  int rq = (lane >> 4) * 4;
  #pragma unroll
  for (int ct = 0; ct < 4; ct++) {
    int c = ct * 16 + m_l;
    float bv = bias[hd * 64 + c];
    #pragma unroll
    for (int r = 0; r < 4; r++) {
      int d = w * 16 + rq + r;
      if (d < NP)
        xout[(size_t)(g * NP + d) * FF + hd * 64 + c] = f2bf(fmaxf(acc[ct][r] + bv, 0.f));
    }
  }
}

// bf16 MFMA GEMM: C[M][N] fp32 = A[M][K]bf16 @ Bt[N][K]bf16^T (+bias).
// 128x128 tile, 4 waves, BK=32, global_load_lds width-16 (m97 structure).
__global__ __launch_bounds__(256) void k_bgemm(
    const ushort_t* __restrict__ A, const ushort_t* __restrict__ Bt,
    const float* __restrict__ bias, float* __restrict__ C,
    int M, int N, int K) {
  __shared__ ushort_t As[128 * 32];
  __shared__ ushort_t Bs[128 * 32];
  int tid = threadIdx.x;
  int w = tid >> 6, l = tid & 63;
  int row0 = blockIdx.y * 128, col0 = blockIdx.x * 128;
  int wr = w >> 1, wc = w & 1;

  f32x4 acc[4][4];
  #pragma unroll
  for (int i = 0; i < 4; i++)
    #pragma unroll
    for (int j = 0; j < 4; j++) acc[i][j] = (f32x4){0.f, 0.f, 0.f, 0.f};

  int srow = w * 32 + (l >> 2);
  int skcol = (l & 3) * 8;
  const ushort_t* Ag = A + (size_t)(row0 + srow) * K + skcol;
  const ushort_t* Bg = Bt + (size_t)(col0 + srow) * K + skcol;
  ushort_t* AsW = &As[w * 1024];
  ushort_t* BsW = &Bs[w * 1024];

  int m_l = l & 15, kq = (l >> 4) * 8;
  const ushort_t* ArdA = &As[(wr * 64 + m_l) * 32 + kq];
  const ushort_t* BrdB = &Bs[(wc * 64 + m_l) * 32 + kq];

  for (int k0 = 0; k0 < K; k0 += 32) {
    gload_lds16(Ag + k0, AsW);
    gload_lds16(Ag + (size_t)16 * K + k0, AsW + 512);
    gload_lds16(Bg + k0, BsW);
    gload_lds16(Bg + (size_t)16 * K + k0, BsW + 512);
    __syncthreads();
    bf16x8 af[4], bfr[4];
    #pragma unroll
    for (int t = 0; t < 4; t++) {
      af[t]  = *(const bf16x8*)(ArdA + t * 16 * 32);
      bfr[t] = *(const bf16x8*)(BrdB + t * 16 * 32);
    }
    #pragma unroll
    for (int mt = 0; mt < 4; mt++)
      #pragma unroll
      for (int nt = 0; nt < 4; nt++)
        acc[mt][nt] = __builtin_amdgcn_mfma_f32_16x16x32_bf16(af[mt], bfr[nt], acc[mt][nt], 0, 0, 0);
    __syncthreads();
  }

  int cl = l & 15, rq = (l >> 4) * 4;
  #pragma unroll
  for (int mt = 0; mt < 4; mt++) {
    #pragma unroll
    for (int nt = 0; nt < 4; nt++) {
      int col = col0 + wc * 64 + nt * 16 + cl;
      float bv = bias ? bias[col] : 0.f;
      #pragma unroll
      for (int r = 0; r < 4; r++) {
        int row = row0 + wr * 64 + mt * 16 + rq + r;
        C[(size_t)row * N + col] = acc[mt][nt][r] + bv;
      }
    }
  }
}

// graph mean pool + GRU input sequence [B,5,1024]=[agent|graph]; bf16 in/out
__global__ void k_pool(const ushort_t* __restrict__ x3, ushort_t* __restrict__ combined) {
  int b = blockIdx.x, tid = threadIdx.x;   // 256 threads
  float a0 = 0.f, a1 = 0.f;
  for (int n = 0; n < NP; n++) {
    const ushort_t* r = x3 + (size_t)(b * NP + n) * FF;
    a0 += bf2f(r[tid]); a1 += bf2f(r[tid + 256]);
  }
  a0 *= (1.f / NP); a1 *= (1.f / NP);
  ushort_t b0 = f2bf(a0), b1v = f2bf(a1);
  for (int t = 0; t < 5; t++) {
    ushort_t* cb = combined + (size_t)(b * 5 + t) * GRUIN;
    const ushort_t* ag = x3 + (size_t)(b * NP + t) * FF;
    cb[tid] = ag[tid];
    cb[tid + 256] = ag[tid + 256];
    cb[512 + tid] = b0;
    cb[768 + tid] = b1v;
  }
}

// GRU: one block per batch element, 5 sequential steps. gi_all already has bih.
__global__ void k_gru(const float* __restrict__ gi_all, const float* __restrict__ h0,
                      const float* __restrict__ Whh, const float* __restrict__ bhh,
                      float* __restrict__ gru_out, float* __restrict__ hlast) {
  int b = blockIdx.x, tid = threadIdx.x;   // 384 threads
  __shared__ float hl[GRUH];
  __shared__ float ghb[384];
  if (tid < GRUH) hl[tid] = h0[b * GRUH + tid];
  for (int t = 0; t < 5; t++) {
    __syncthreads();
    float acc = bhh[tid];
    for (int k = 0; k < GRUH; k++) acc += hl[k] * Whh[k * 384 + tid];
    ghb[tid] = acc;
    __syncthreads();
    if (tid < GRUH) {
      const float* gi = gi_all + (size_t)(b * 5 + t) * 384;
      float r = 1.f / (1.f + expf(-(gi[tid] + ghb[tid])));
      float z = 1.f / (1.f + expf(-(gi[128 + tid] + ghb[128 + tid])));
      float nn = tanhf(gi[256 + tid] + r * ghb[256 + tid]);
      float hn = (1.f - z) * nn + z * hl[tid];
      gru_out[(size_t)(b * 5 + t) * GRUH + tid] = hn;
      hl[tid] = hn;
    }
  }
  __syncthreads();
  if (tid < GRUH) hlast[b * GRUH + tid] = hl[tid];
}

// fc1(relu) + fc2 + action_std, one block (64 thr) per (b,t) row
__global__ void k_fc(const float* __restrict__ gru_out, const float* __restrict__ fc1W,
                     const float* __restrict__ fc1b, const float* __restrict__ fc2W,
                     const float* __restrict__ fc2b, const float* __restrict__ log_std,
                     float* __restrict__ dout) {
  int row = blockIdx.x, tid = threadIdx.x;   // 64 threads
  __shared__ float gbuf[GRUH];
  __shared__ float f1[64];
  gbuf[tid] = gru_out[(size_t)row * GRUH + tid];
  gbuf[tid + 64] = gru_out[(size_t)row * GRUH + 64 + tid];
  __syncthreads();
  float acc = fc1b[tid];
  for (int k = 0; k < GRUH; k++) acc += gbuf[k] * fc1W[k * 64 + tid];
  f1[tid] = fmaxf(acc, 0.f);
  __syncthreads();
  if (tid < 3) {
    float o = fc2b[tid];
    for (int j = 0; j < 64; j++) o += f1[j] * fc2W[j * 3 + tid];
    dout[row * 3 + tid] = o;
    float ls = log_std[tid];
    ls = fminf(fmaxf(ls, -20.f), 2.f);
    dout[7680 + row * 3 + tid] = expf(ls);
  }
}

extern "C" void kernel_launch(void* const* d_in, const int* in_sizes, int n_in,
                              void* d_out, int out_size, void* d_ws, size_t ws_size,
                              hipStream_t stream) {
  const float* x      = (const float*)d_in[0];
  const int*   ei     = (const int*)d_in[1];
  const float* eattr  = (const float*)d_in[2];
  const float* hstate = (const float*)d_in[3];
  const float* W1  = (const float*)d_in[4];
  const float* as1 = (const float*)d_in[5];
  const float* ad1 = (const float*)d_in[6];
  const float* We1 = (const float*)d_in[7];
  const float* ae1 = (const float*)d_in[8];
  const float* b1  = (const float*)d_in[9];
  const float* W2  = (const float*)d_in[10];
  const float* as2 = (const float*)d_in[11];
  const float* ad2 = (const float*)d_in[12];
  const float* We2 = (const float*)d_in[13];
  const float* ae2 = (const float*)d_in[14];
  const float* b2  = (const float*)d_in[15];
  const float* W3  = (const float*)d_in[16];
  const float* as3 = (const float*)d_in[17];
  const float* ad3 = (const float*)d_in[18];
  const float* We3 = (const float*)d_in[19];
  const float* ae3 = (const float*)d_in[20];
  const float* b3  = (const float*)d_in[21];
  const float* Wih = (const float*)d_in[22];
  const float* Whh = (const float*)d_in[23];
  const float* bih = (const float*)d_in[24];
  const float* bhh = (const float*)d_in[25];
  const float* fc1W = (const float*)d_in[26];
  const float* fc1b = (const float*)d_in[27];
  const float* fc2W = (const float*)d_in[28];
  const float* fc2b = (const float*)d_in[29];
  const float* lstd = (const float*)d_in[30];

  float* ws = (float*)d_ws;
  float*   hbuf = ws;                                  // 13,107,200 floats
  ushort_t* xbf = (ushort_t*)(ws + 13107200);          // 13,107,200 ushorts
  float* p = ws + 13107200 + 6553600;
  float* lattr = p;           p += 25600;
  float* eea   = p;           p += 204800;
  float* wdot  = p;           p += 32;
  int*   rowp  = (int*)p;     p += 32768;
  int*   esrc  = (int*)p;     p += 204800;
  ushort_t* w2t  = (ushort_t*)p;  p += 131072;   // 262144 ushorts
  ushort_t* w3t  = (ushort_t*)p;  p += 131072;
  ushort_t* wiht = (ushort_t*)p;  p += 196608;   // 393216 ushorts
  ushort_t* cbf  = (ushort_t*)p;  p += 1310720;  // 2,621,440 ushorts
  float* gi_all  = p;         p += 983040;       // [2560][384]
  float* gru_out = p;         p += 327680;
  float* dout = (float*)d_out;

  k_wedot<<<3, 512, 0, stream>>>(We1, ae1, We2, ae2, We3, ae3, wdot);
  k_csr<<<BB, 256, 0, stream>>>(ei, eattr, rowp, esrc, eea, lattr);
  k_cvt_t<<<dim3(16, 16), 256, 0, stream>>>(W2, w2t, FF, FF);
  k_cvt_t<<<dim3(16, 16), 256, 0, stream>>>(W3, w3t, FF, FF);
  k_cvt_t<<<dim3(12, 32), 256, 0, stream>>>(Wih, wiht, GRUIN, 384);

  // layer 1: fused conv1 + dots + gat -> xbf (bf16)
  k_gatm<<<dim3(BB, HH), 256, 0, stream>>>(nullptr, x, W1, xbf, as1, ad1,
                                           rowp, esrc, eea, lattr, wdot, b1, 0, 0);
  // layer 2: h2 = x1_bf @ W2t -> hbuf (fp32); fused dots + gat -> xbf
  k_bgemm<<<dim3(4, 200), 256, 0, stream>>>(xbf, w2t, nullptr, hbuf, NN, FF, FF);
  k_gatm<<<dim3(BB, HH), 256, 0, stream>>>(hbuf, nullptr, nullptr, xbf, as2, ad2,
                                           rowp, esrc, eea, lattr, wdot, b2, 1, 1);
  // layer 3: h3 = x2_bf @ W3t -> hbuf; fused dots + gat -> xbf (x3 bf16)
  k_bgemm<<<dim3(4, 200), 256, 0, stream>>>(xbf, w3t, nullptr, hbuf, NN, FF, FF);
  k_gatm<<<dim3(BB, HH), 256, 0, stream>>>(hbuf, nullptr, nullptr, xbf, as3, ad3,
                                           rowp, esrc, eea, lattr, wdot, b3, 2, 1);

  // pool (bf16 combined) + GRU input GEMM (adds bih)
  k_pool<<<BB, 256, 0, stream>>>(xbf, cbf);
  k_bgemm<<<dim3(3, 20), 256, 0, stream>>>(cbf, wiht, bih, gi_all, 2560, 384, GRUIN);

  // GRU scan + heads
  k_gru<<<BB, 384, 0, stream>>>(gi_all, hstate, Whh, bhh, gru_out, dout + 15360);
  k_fc<<<2560, 64, 0, stream>>>(gru_out, fc1W, fc1b, fc2W, fc2b, lstd, dout);
}

// Round 4
// 379.076 us; speedup vs baseline: 2.5240x; 1.1406x over previous
//
#include <hip/hip_runtime.h>
#include <math.h>

#define NN 25600      // total nodes
#define BB 512        // graphs
#define NP 50         // nodes per graph
#define EPG 400       // edges per graph
#define EE 204800     // total edges
#define HH 8
#define CC 64
#define FF 512
#define GRUH 128
#define GRUIN 1024

typedef unsigned short ushort_t;
typedef __attribute__((ext_vector_type(8))) short bf16x8;
typedef __attribute__((ext_vector_type(4))) float f32x4;

__device__ __forceinline__ float wave_reduce_sum(float v) {
  #pragma unroll
  for (int m = 32; m >= 1; m >>= 1) v += __shfl_xor(v, m, 64);
  return v;
}

__device__ __forceinline__ ushort_t f2bf(float x) {
  union { float f; unsigned int u; } v; v.f = x;
  unsigned int r = v.u + 0x7fffu + ((v.u >> 16) & 1u);   // RNE
  return (ushort_t)(r >> 16);
}

__device__ __forceinline__ float bf2f(ushort_t u) {
  union { unsigned int u; float f; } v; v.u = ((unsigned int)u) << 16;
  return v.f;
}

__device__ __forceinline__ void gload_lds16(const ushort_t* g, ushort_t* l) {
  __builtin_amdgcn_global_load_lds(
      (const __attribute__((address_space(1))) void*)g,
      (__attribute__((address_space(3))) void*)l, 16, 0, 0);
}

// we_dot[l*8+h] = sum_c We_l[h*64+c] * ae_l[h*64+c]
__global__ void k_wedot(const float* __restrict__ We1, const float* __restrict__ ae1,
                        const float* __restrict__ We2, const float* __restrict__ ae2,
                        const float* __restrict__ We3, const float* __restrict__ ae3,
                        float* __restrict__ wdot) {
  const float* We = blockIdx.x == 0 ? We1 : (blockIdx.x == 1 ? We2 : We3);
  const float* ae = blockIdx.x == 0 ? ae1 : (blockIdx.x == 1 ? ae2 : ae3);
  int head = threadIdx.x >> 6, lane = threadIdx.x & 63;
  float v = We[head * 64 + lane] * ae[head * 64 + lane];
  v = wave_reduce_sum(v);
  if (lane == 0) wdot[blockIdx.x * 8 + head] = v;
}

// Per-graph CSR by dst (local ids), plus loop_attr = mean incoming edge_attr.
__global__ void k_csr(const int* __restrict__ ei, const float* __restrict__ eattr,
                      int* __restrict__ rowp, int* __restrict__ esrc,
                      float* __restrict__ eea, float* __restrict__ lattr) {
  int g = blockIdx.x, tid = threadIdx.x;
  __shared__ int cnt[NP];
  __shared__ float esum[NP];
  __shared__ int rp[NP + 1];
  __shared__ int cur[NP];
  if (tid < NP) { cnt[tid] = 0; esum[tid] = 0.f; }
  __syncthreads();
  for (int e = tid; e < EPG; e += blockDim.x) {
    int ge = g * EPG + e;
    int dl = ei[EE + ge] - g * NP;
    atomicAdd(&cnt[dl], 1);
    atomicAdd(&esum[dl], eattr[ge]);
  }
  __syncthreads();
  if (tid == 0) {
    int s = 0;
    for (int i = 0; i < NP; i++) { rp[i] = s; cur[i] = s; s += cnt[i]; }
    rp[NP] = s;
  }
  __syncthreads();
  if (tid <= NP) rowp[g * 64 + tid] = rp[tid];
  if (tid < NP) lattr[g * NP + tid] = esum[tid] / (float)max(cnt[tid], 1);
  for (int e = tid; e < EPG; e += blockDim.x) {
    int ge = g * EPG + e;
    int sl = ei[ge] - g * NP;
    int dl = ei[EE + ge] - g * NP;
    int pos = atomicAdd(&cur[dl], 1);
    esrc[g * EPG + pos] = sl;
    eea[g * EPG + pos] = eattr[ge];
  }
}

// transpose + fp32->bf16: Wt[n][k] = bf16(W[k][n]); K,N multiples of 32
__global__ __launch_bounds__(256) void k_cvt_t(const float* __restrict__ W,
                                               ushort_t* __restrict__ Wt,
                                               int K, int N) {
  __shared__ float t[32][33];
  int n0 = blockIdx.x * 32, k0 = blockIdx.y * 32;
  int tx = threadIdx.x & 31, ty = threadIdx.x >> 5;   // ty 0..7
  #pragma unroll
  for (int i = 0; i < 4; i++)
    t[ty + i * 8][tx] = W[(size_t)(k0 + ty + i * 8) * N + n0 + tx];
  __syncthreads();
  #pragma unroll
  for (int i = 0; i < 4; i++)
    Wt[(size_t)(n0 + ty + i * 8) * K + k0 + tx] = f2bf(t[tx][ty + i * 8]);
}

// Fused GAT layer, all-MFMA (one block per graph,head):
//   stage h (row-major + swizzled-transposed, bf16)
//   -> MFMA dots (a_src/a_dst x h^T)  -> softmax over CSR -> bf16 Am
//   -> MFMA ht @ Am -> relu+bias -> packed bf16 out.
__global__ __launch_bounds__(256) void k_gatm(
    const float* __restrict__ hin,       // fp32 [N][512] (layers 2,3)
    const float* __restrict__ xin,       // raw x [N][4] (layer 1) or null
    const float* __restrict__ W1,        // [4][512] (layer 1) or null
    ushort_t* __restrict__ xout,         // bf16 [N][512]
    const float* __restrict__ a_src, const float* __restrict__ a_dst,  // [8*64]
    const int* __restrict__ rowp, const int* __restrict__ esrcg,
    const float* __restrict__ eeag, const float* __restrict__ lattr,
    const float* __restrict__ wdot_all, const float* __restrict__ bias,
    int layer, int self_loops) {
  int g = blockIdx.x, hd = blockIdx.y, tid = threadIdx.x;
  int w = tid >> 6, lane = tid & 63;

  // ht[c][s^swz(c)] bf16, stride 72 (144 B, 16B-aligned rows); swz(c)=c&56
  __shared__ __align__(16) ushort_t ht[64 * 72];
  // phase A: hrow[s][c]; phase B (after re-zero): Am[d][s]
  __shared__ __align__(16) ushort_t hAm[64 * 72];
  __shared__ __align__(16) ushort_t ab[16 * 72];   // rows 0: a_src, 1: a_dst
  __shared__ float ssl[64], sdl[64], lat[64];
  __shared__ float albuf[EPG], eaS[EPG];
  __shared__ int esS[EPG];
  __shared__ int rp[64];

  // ---- P0: constants, edges, zero ht ----
  float wdot = wdot_all[layer * 8 + hd];
  float w1c0 = 0.f, w1c1 = 0.f, w1c2 = 0.f, w1c3 = 0.f;
  if (W1) {
    w1c0 = W1[hd * 64 + lane];        w1c1 = W1[512 + hd * 64 + lane];
    w1c2 = W1[1024 + hd * 64 + lane]; w1c3 = W1[1536 + hd * 64 + lane];
  }
  for (int i = tid; i < EPG; i += 256) { esS[i] = esrcg[g * EPG + i]; eaS[i] = eeag[g * EPG + i]; }
  if (tid <= NP) rp[tid] = rowp[g * 64 + tid];
  if (tid < NP) lat[tid] = lattr[g * NP + tid];
  if (tid < 64) ab[tid] = f2bf(a_src[hd * 64 + tid]);
  else if (tid < 128) ab[72 + (tid - 64)] = f2bf(a_dst[hd * 64 + (tid - 64)]);
  {
    uint4* z = (uint4*)ht;          // 64*72*2 B = 9216 B = 576 uint4
    uint4 zz = make_uint4(0u, 0u, 0u, 0u);
    for (int i = tid; i < 576; i += 256) z[i] = zz;
  }
  __syncthreads();

  // ---- P1: stage h (bf16) into hrow + swizzled ht ----
  #pragma unroll
  for (int i = 0; i < 13; i++) {
    int s = w + 4 * i;
    if (s < NP) {
      float hv;
      if (W1) {
        const float4 xv = *(const float4*)(xin + (size_t)(g * NP + s) * 4);
        hv = xv.x * w1c0 + xv.y * w1c1 + xv.z * w1c2 + xv.w * w1c3;
      } else {
        hv = hin[(size_t)(g * NP + s) * FF + hd * 64 + lane];
      }
      ushort_t hb = f2bf(hv);
      hAm[s * 72 + lane] = hb;                    // hrow[s][c], conflict-free
      ht[lane * 72 + (s ^ (lane & 56))] = hb;     // swizzled transpose
    }
  }
  __syncthreads();

  // ---- P2: dots via MFMA: D[m=vec][n=s] = ab @ hrow^T ----
  int m_l = lane & 15, kq8 = (lane >> 4) * 8;
  {
    int s0 = w * 16;
    f32x4 dacc = (f32x4){0.f, 0.f, 0.f, 0.f};
    #pragma unroll
    for (int kc = 0; kc < 2; kc++) {
      bf16x8 a = *(const bf16x8*)(&ab[m_l * 72 + kc * 32 + kq8]);
      bf16x8 b = *(const bf16x8*)(&hAm[(s0 + m_l) * 72 + kc * 32 + kq8]);
      dacc = __builtin_amdgcn_mfma_f32_16x16x32_bf16(a, b, dacc, 0, 0, 0);
    }
    if (lane < 16) { ssl[s0 + lane] = dacc[0]; sdl[s0 + lane] = dacc[1]; }
  }
  __syncthreads();

  // ---- P3: re-zero hAm -> Am ----
  {
    uint4* z = (uint4*)hAm;
    uint4 zz = make_uint4(0u, 0u, 0u, 0u);
    for (int i = tid; i < 576; i += 256) z[i] = zz;
  }
  __syncthreads();

  // ---- P4: per-dst softmax -> bf16 alpha row (RMW handles duplicate edges) ----
  if (tid < NP) {
    int d = tid;
    int e0 = rp[d], e1 = rp[d + 1];
    float sd = sdl[d];
    float m = -1e30f;
    for (int e = e0; e < e1; e++) {
      float al = ssl[esS[e]] + sd + eaS[e] * wdot;
      al = al > 0.f ? al : 0.2f * al;   // leaky_relu 0.2
      albuf[e] = al;
      m = fmaxf(m, al);
    }
    float al_loop = 0.f;
    if (self_loops) {
      al_loop = ssl[d] + sd + lat[d] * wdot;
      al_loop = al_loop > 0.f ? al_loop : 0.2f * al_loop;
      m = fmaxf(m, al_loop);
    }
    if (e1 > e0 || self_loops) {
      float denom = 0.f;
      for (int e = e0; e < e1; e++) { float p = expf(albuf[e] - m); albuf[e] = p; denom += p; }
      float ploop = 0.f;
      if (self_loops) { ploop = expf(al_loop - m); denom += ploop; }
      float inv = 1.f / (denom + 1e-16f);
      for (int e = e0; e < e1; e++) {
        int s = esS[e];
        float prev = bf2f(hAm[d * 72 + s]);
        hAm[d * 72 + s] = f2bf(prev + albuf[e] * inv);
      }
      if (self_loops) {
        float prev = bf2f(hAm[d * 72 + d]);
        hAm[d * 72 + d] = f2bf(prev + ploop * inv);
      }
    }
  }
  __syncthreads();

  // ---- P5: out-MFMA: D[m=c][n=d] = ht @ Am^T; wave w owns d in [w*16, w*16+16) ----
  int d0 = w * 16;
  f32x4 acc[4];
  #pragma unroll
  for (int ct = 0; ct < 4; ct++) acc[ct] = (f32x4){0.f, 0.f, 0.f, 0.f};
  #pragma unroll
  for (int kc = 0; kc < 2; kc++) {
    bf16x8 bfrag = *(const bf16x8*)(&hAm[(d0 + m_l) * 72 + kc * 32 + kq8]);
    #pragma unroll
    for (int ct = 0; ct < 4; ct++) {
      int m = ct * 16 + m_l;
      bf16x8 afrag = *(const bf16x8*)(&ht[m * 72 + ((kc * 32 + kq8) ^ (m & 56))]);
      acc[ct] = __builtin_amdgcn_mfma_f32_16x16x32_bf16(afrag, bfrag, acc[ct], 0, 0, 0);
    }
  }

  // epilogue: row=(lane>>4)*4+reg = c (consecutive!), col=lane&15 = d
  int d = d0 + m_l, rq = (lane >> 4) * 4;
  if (d < NP) {
    #pragma unroll
    for (int ct = 0; ct < 4; ct++) {
      int cb = ct * 16 + rq;
      const float4 bv = *(const float4*)(&bias[hd * 64 + cb]);
      union { ushort_t u[4]; uint2 v; } pk;
      pk.u[0] = f2bf(fmaxf(acc[ct][0] + bv.x, 0.f));
      pk.u[1] = f2bf(fmaxf(acc[ct][1] + bv.y, 0.f));
      pk.u[2] = f2bf(fmaxf(acc[ct][2] + bv.z, 0.f));
      pk.u[3] = f2bf(fmaxf(acc[ct][3] + bv.w, 0.f));
      *(uint2*)(&xout[(size_t)(g * NP + d) * FF + hd * 64 + cb]) = pk.v;
    }
  }
}

// bf16 MFMA GEMM: C[M][N] fp32 = A[M][K]bf16 @ Bt[N][K]bf16^T (+bias).
// 128x128 tile, 4 waves, BK=32, global_load_lds width-16 (m97 structure).
__global__ __launch_bounds__(256) void k_bgemm(
    const ushort_t* __restrict__ A, const ushort_t* __restrict__ Bt,
    const float* __restrict__ bias, float* __restrict__ C,
    int M, int N, int K) {
  __shared__ ushort_t As[128 * 32];
  __shared__ ushort_t Bs[128 * 32];
  int tid = threadIdx.x;
  int w = tid >> 6, l = tid & 63;
  int row0 = blockIdx.y * 128, col0 = blockIdx.x * 128;
  int wr = w >> 1, wc = w & 1;

  f32x4 acc[4][4];
  #pragma unroll
  for (int i = 0; i < 4; i++)
    #pragma unroll
    for (int j = 0; j < 4; j++) acc[i][j] = (f32x4){0.f, 0.f, 0.f, 0.f};

  int srow = w * 32 + (l >> 2);
  int skcol = (l & 3) * 8;
  const ushort_t* Ag = A + (size_t)(row0 + srow) * K + skcol;
  const ushort_t* Bg = Bt + (size_t)(col0 + srow) * K + skcol;
  ushort_t* AsW = &As[w * 1024];
  ushort_t* BsW = &Bs[w * 1024];

  int m_l = l & 15, kq = (l >> 4) * 8;
  const ushort_t* ArdA = &As[(wr * 64 + m_l) * 32 + kq];
  const ushort_t* BrdB = &Bs[(wc * 64 + m_l) * 32 + kq];

  for (int k0 = 0; k0 < K; k0 += 32) {
    gload_lds16(Ag + k0, AsW);
    gload_lds16(Ag + (size_t)16 * K + k0, AsW + 512);
    gload_lds16(Bg + k0, BsW);
    gload_lds16(Bg + (size_t)16 * K + k0, BsW + 512);
    __syncthreads();
    bf16x8 af[4], bfr[4];
    #pragma unroll
    for (int t = 0; t < 4; t++) {
      af[t]  = *(const bf16x8*)(ArdA + t * 16 * 32);
      bfr[t] = *(const bf16x8*)(BrdB + t * 16 * 32);
    }
    #pragma unroll
    for (int mt = 0; mt < 4; mt++)
      #pragma unroll
      for (int nt = 0; nt < 4; nt++)
        acc[mt][nt] = __builtin_amdgcn_mfma_f32_16x16x32_bf16(af[mt], bfr[nt], acc[mt][nt], 0, 0, 0);
    __syncthreads();
  }

  int cl = l & 15, rq = (l >> 4) * 4;
  #pragma unroll
  for (int mt = 0; mt < 4; mt++) {
    #pragma unroll
    for (int nt = 0; nt < 4; nt++) {
      int col = col0 + wc * 64 + nt * 16 + cl;
      float bv = bias ? bias[col] : 0.f;
      #pragma unroll
      for (int r = 0; r < 4; r++) {
        int row = row0 + wr * 64 + mt * 16 + rq + r;
        C[(size_t)row * N + col] = acc[mt][nt][r] + bv;
      }
    }
  }
}

// graph mean pool + GRU input sequence [B,5,1024]=[agent|graph]; bf16 in/out
__global__ void k_pool(const ushort_t* __restrict__ x3, ushort_t* __restrict__ combined) {
  int b = blockIdx.x, tid = threadIdx.x;   // 256 threads
  float a0 = 0.f, a1 = 0.f;
  for (int n = 0; n < NP; n++) {
    const ushort_t* r = x3 + (size_t)(b * NP + n) * FF;
    a0 += bf2f(r[tid]); a1 += bf2f(r[tid + 256]);
  }
  a0 *= (1.f / NP); a1 *= (1.f / NP);
  ushort_t b0 = f2bf(a0), b1v = f2bf(a1);
  for (int t = 0; t < 5; t++) {
    ushort_t* cb = combined + (size_t)(b * 5 + t) * GRUIN;
    const ushort_t* ag = x3 + (size_t)(b * NP + t) * FF;
    cb[tid] = ag[tid];
    cb[tid + 256] = ag[tid + 256];
    cb[512 + tid] = b0;
    cb[768 + tid] = b1v;
  }
}

// GRU: one block per batch element, 5 sequential steps. gi_all already has bih.
__global__ void k_gru(const float* __restrict__ gi_all, const float* __restrict__ h0,
                      const float* __restrict__ Whh, const float* __restrict__ bhh,
                      float* __restrict__ gru_out, float* __restrict__ hlast) {
  int b = blockIdx.x, tid = threadIdx.x;   // 384 threads
  __shared__ float hl[GRUH];
  __shared__ float ghb[384];
  if (tid < GRUH) hl[tid] = h0[b * GRUH + tid];
  for (int t = 0; t < 5; t++) {
    __syncthreads();
    float acc = bhh[tid];
    for (int k = 0; k < GRUH; k++) acc += hl[k] * Whh[k * 384 + tid];
    ghb[tid] = acc;
    __syncthreads();
    if (tid < GRUH) {
      const float* gi = gi_all + (size_t)(b * 5 + t) * 384;
      float r = 1.f / (1.f + expf(-(gi[tid] + ghb[tid])));
      float z = 1.f / (1.f + expf(-(gi[128 + tid] + ghb[128 + tid])));
      float nn = tanhf(gi[256 + tid] + r * ghb[256 + tid]);
      float hn = (1.f - z) * nn + z * hl[tid];
      gru_out[(size_t)(b * 5 + t) * GRUH + tid] = hn;
      hl[tid] = hn;
    }
  }
  __syncthreads();
  if (tid < GRUH) hlast[b * GRUH + tid] = hl[tid];
}

// fc1(relu) + fc2 + action_std, one block (64 thr) per (b,t) row
__global__ void k_fc(const float* __restrict__ gru_out, const float* __restrict__ fc1W,
                     const float* __restrict__ fc1b, const float* __restrict__ fc2W,
                     const float* __restrict__ fc2b, const float* __restrict__ log_std,
                     float* __restrict__ dout) {
  int row = blockIdx.x, tid = threadIdx.x;   // 64 threads
  __shared__ float gbuf[GRUH];
  __shared__ float f1[64];
  gbuf[tid] = gru_out[(size_t)row * GRUH + tid];
  gbuf[tid + 64] = gru_out[(size_t)row * GRUH + 64 + tid];
  __syncthreads();
  float acc = fc1b[tid];
  for (int k = 0; k < GRUH; k++) acc += gbuf[k] * fc1W[k * 64 + tid];
  f1[tid] = fmaxf(acc, 0.f);
  __syncthreads();
  if (tid < 3) {
    float o = fc2b[tid];
    for (int j = 0; j < 64; j++) o += f1[j] * fc2W[j * 3 + tid];
    dout[row * 3 + tid] = o;
    float ls = log_std[tid];
    ls = fminf(fmaxf(ls, -20.f), 2.f);
    dout[7680 + row * 3 + tid] = expf(ls);
  }
}

extern "C" void kernel_launch(void* const* d_in, const int* in_sizes, int n_in,
                              void* d_out, int out_size, void* d_ws, size_t ws_size,
                              hipStream_t stream) {
  const float* x      = (const float*)d_in[0];
  const int*   ei     = (const int*)d_in[1];
  const float* eattr  = (const float*)d_in[2];
  const float* hstate = (const float*)d_in[3];
  const float* W1  = (const float*)d_in[4];
  const float* as1 = (const float*)d_in[5];
  const float* ad1 = (const float*)d_in[6];
  const float* We1 = (const float*)d_in[7];
  const float* ae1 = (const float*)d_in[8];
  const float* b1  = (const float*)d_in[9];
  const float* W2  = (const float*)d_in[10];
  const float* as2 = (const float*)d_in[11];
  const float* ad2 = (const float*)d_in[12];
  const float* We2 = (const float*)d_in[13];
  const float* ae2 = (const float*)d_in[14];
  const float* b2  = (const float*)d_in[15];
  const float* W3  = (const float*)d_in[16];
  const float* as3 = (const float*)d_in[17];
  const float* ad3 = (const float*)d_in[18];
  const float* We3 = (const float*)d_in[19];
  const float* ae3 = (const float*)d_in[20];
  const float* b3  = (const float*)d_in[21];
  const float* Wih = (const float*)d_in[22];
  const float* Whh = (const float*)d_in[23];
  const float* bih = (const float*)d_in[24];
  const float* bhh = (const float*)d_in[25];
  const float* fc1W = (const float*)d_in[26];
  const float* fc1b = (const float*)d_in[27];
  const float* fc2W = (const float*)d_in[28];
  const float* fc2b = (const float*)d_in[29];
  const float* lstd = (const float*)d_in[30];

  float* ws = (float*)d_ws;
  float*   hbuf = ws;                                  // 13,107,200 floats
  ushort_t* xbf = (ushort_t*)(ws + 13107200);          // 13,107,200 ushorts
  float* p = ws + 13107200 + 6553600;
  float* lattr = p;           p += 25600;
  float* eea   = p;           p += 204800;
  float* wdot  = p;           p += 32;
  int*   rowp  = (int*)p;     p += 32768;
  int*   esrc  = (int*)p;     p += 204800;
  ushort_t* w2t  = (ushort_t*)p;  p += 131072;   // 262144 ushorts
  ushort_t* w3t  = (ushort_t*)p;  p += 131072;
  ushort_t* wiht = (ushort_t*)p;  p += 196608;   // 393216 ushorts
  ushort_t* cbf  = (ushort_t*)p;  p += 1310720;  // 2,621,440 ushorts
  float* gi_all  = p;         p += 983040;       // [2560][384]
  float* gru_out = p;         p += 327680;
  float* dout = (float*)d_out;

  k_wedot<<<3, 512, 0, stream>>>(We1, ae1, We2, ae2, We3, ae3, wdot);
  k_csr<<<BB, 256, 0, stream>>>(ei, eattr, rowp, esrc, eea, lattr);
  k_cvt_t<<<dim3(16, 16), 256, 0, stream>>>(W2, w2t, FF, FF);
  k_cvt_t<<<dim3(16, 16), 256, 0, stream>>>(W3, w3t, FF, FF);
  k_cvt_t<<<dim3(12, 32), 256, 0, stream>>>(Wih, wiht, GRUIN, 384);

  // layer 1: fused conv1 + dots + gat -> xbf (bf16)
  k_gatm<<<dim3(BB, HH), 256, 0, stream>>>(nullptr, x, W1, xbf, as1, ad1,
                                           rowp, esrc, eea, lattr, wdot, b1, 0, 0);
  // layer 2: h2 = x1_bf @ W2t -> hbuf (fp32); fused dots + gat -> xbf
  k_bgemm<<<dim3(4, 200), 256, 0, stream>>>(xbf, w2t, nullptr, hbuf, NN, FF, FF);
  k_gatm<<<dim3(BB, HH), 256, 0, stream>>>(hbuf, nullptr, nullptr, xbf, as2, ad2,
                                           rowp, esrc, eea, lattr, wdot, b2, 1, 1);
  // layer 3: h3 = x2_bf @ W3t -> hbuf; fused dots + gat -> xbf (x3 bf16)
  k_bgemm<<<dim3(4, 200), 256, 0, stream>>>(xbf, w3t, nullptr, hbuf, NN, FF, FF);
  k_gatm<<<dim3(BB, HH), 256, 0, stream>>>(hbuf, nullptr, nullptr, xbf, as3, ad3,
                                           rowp, esrc, eea, lattr, wdot, b3, 2, 1);

  // pool (bf16 combined) + GRU input GEMM (adds bih)
  k_pool<<<BB, 256, 0, stream>>>(xbf, cbf);
  k_bgemm<<<dim3(3, 20), 256, 0, stream>>>(cbf, wiht, bih, gi_all, 2560, 384, GRUIN);

  // GRU scan + heads
  k_gru<<<BB, 384, 0, stream>>>(gi_all, hstate, Whh, bhh, gru_out, dout + 15360);
  k_fc<<<2560, 64, 0, stream>>>(gru_out, fc1W, fc1b, fc2W, fc2b, lstd, dout);
}

// Round 5
// 364.747 us; speedup vs baseline: 2.6232x; 1.0393x over previous
//
#include <hip/hip_runtime.h>
#include <math.h>

#define NN 25600      // total nodes
#define BB 512        // graphs
#define NP 50         // nodes per graph
#define EPG 400       // edges per graph
#define EE 204800     // total edges
#define HH 8
#define CC 64
#define FF 512
#define GRUH 128
#define GRUIN 1024
#define NTP 25664     // hT row stride (25600 + 64 pad)

typedef unsigned short ushort_t;
typedef __attribute__((ext_vector_type(8))) short bf16x8;
typedef __attribute__((ext_vector_type(4))) float f32x4;

__device__ __forceinline__ float wave_reduce_sum(float v) {
  #pragma unroll
  for (int m = 32; m >= 1; m >>= 1) v += __shfl_xor(v, m, 64);
  return v;
}

__device__ __forceinline__ ushort_t f2bf(float x) {
  union { float f; unsigned int u; } v; v.f = x;
  unsigned int r = v.u + 0x7fffu + ((v.u >> 16) & 1u);   // RNE
  return (ushort_t)(r >> 16);
}

__device__ __forceinline__ float bf2f(ushort_t u) {
  union { unsigned int u; float f; } v; v.u = ((unsigned int)u) << 16;
  return v.f;
}

__device__ __forceinline__ void gload_lds16(const ushort_t* g, ushort_t* l) {
  __builtin_amdgcn_global_load_lds(
      (const __attribute__((address_space(1))) void*)g,
      (__attribute__((address_space(3))) void*)l, 16, 0, 0);
}

// we_dot[l*8+h] = sum_c We_l[h*64+c] * ae_l[h*64+c]
__global__ void k_wedot(const float* __restrict__ We1, const float* __restrict__ ae1,
                        const float* __restrict__ We2, const float* __restrict__ ae2,
                        const float* __restrict__ We3, const float* __restrict__ ae3,
                        float* __restrict__ wdot) {
  const float* We = blockIdx.x == 0 ? We1 : (blockIdx.x == 1 ? We2 : We3);
  const float* ae = blockIdx.x == 0 ? ae1 : (blockIdx.x == 1 ? ae2 : ae3);
  int head = threadIdx.x >> 6, lane = threadIdx.x & 63;
  float v = We[head * 64 + lane] * ae[head * 64 + lane];
  v = wave_reduce_sum(v);
  if (lane == 0) wdot[blockIdx.x * 8 + head] = v;
}

// Per-graph: lattr (mean incoming edge_attr per node) + min/max edge_attr
// (incl. lattr) for the bounded-softmax-max trick.
__global__ void k_lattr(const int* __restrict__ ei, const float* __restrict__ eattr,
                        float* __restrict__ lattr, float* __restrict__ gmm) {
  int g = blockIdx.x, tid = threadIdx.x;
  __shared__ float esum[NP];
  __shared__ int cnt[NP];
  __shared__ unsigned int mn, mx;
  if (tid < NP) { esum[tid] = 0.f; cnt[tid] = 0; }
  if (tid == 0) { mn = 0x7f7fffffu; mx = 0u; }
  __syncthreads();
  for (int e = tid; e < EPG; e += 256) {
    int ge = g * EPG + e;
    int d = ei[EE + ge] - g * NP;
    float a = eattr[ge];                      // a >= 0 by construction
    atomicAdd(&esum[d], a);
    atomicAdd(&cnt[d], 1);
    atomicMax(&mx, __float_as_uint(a));
    atomicMin(&mn, __float_as_uint(a));
  }
  __syncthreads();
  if (tid < NP) {
    float la = esum[tid] / (float)max(cnt[tid], 1);
    lattr[g * NP + tid] = la;
    atomicMax(&mx, __float_as_uint(la));
    atomicMin(&mn, __float_as_uint(la));
  }
  __syncthreads();
  if (tid == 0) { gmm[g * 2] = __uint_as_float(mn); gmm[g * 2 + 1] = __uint_as_float(mx); }
}

// transpose + fp32->bf16: Wt[n][k] = bf16(W[k][n]); K,N multiples of 32
__global__ __launch_bounds__(256) void k_cvt_t(const float* __restrict__ W,
                                               ushort_t* __restrict__ Wt,
                                               int K, int N) {
  __shared__ float t[32][33];
  int n0 = blockIdx.x * 32, k0 = blockIdx.y * 32;
  int tx = threadIdx.x & 31, ty = threadIdx.x >> 5;   // ty 0..7
  #pragma unroll
  for (int i = 0; i < 4; i++)
    t[ty + i * 8][tx] = W[(size_t)(k0 + ty + i * 8) * N + n0 + tx];
  __syncthreads();
  #pragma unroll
  for (int i = 0; i < 4; i++)
    Wt[(size_t)(n0 + ty + i * 8) * K + k0 + tx] = f2bf(t[tx][ty + i * 8]);
}

// Transposed GEMM with fused attention dots:
//   hT[f][n] = sum_k Wt[f][k] * X[n][k]   (bf16 out, fp32 acc)
//   ssg[n*8+hd] = sum_c h[n][hd*64+c]*a_src[hd*64+c]  (exactly-once stores)
// A-operand = Wt [512][512], B-operand = X [25600][512]. M=512, N=25600, K=512.
__global__ __launch_bounds__(256) void k_bgemmT(
    const ushort_t* __restrict__ Wt, const ushort_t* __restrict__ X,
    const float* __restrict__ a_src, const float* __restrict__ a_dst,
    ushort_t* __restrict__ hT, float* __restrict__ ssg, float* __restrict__ sdg) {
  __shared__ ushort_t As[128 * 32];
  __shared__ ushort_t Bs[128 * 32];
  int tid = threadIdx.x;
  int w = tid >> 6, l = tid & 63;
  int row0 = blockIdx.y * 128;   // feature tile
  int col0 = blockIdx.x * 128;   // node tile
  int wr = w >> 1, wc = w & 1;

  f32x4 acc[4][4];
  #pragma unroll
  for (int i = 0; i < 4; i++)
    #pragma unroll
    for (int j = 0; j < 4; j++) acc[i][j] = (f32x4){0.f, 0.f, 0.f, 0.f};

  int srow = w * 32 + (l >> 2);
  int skcol = (l & 3) * 8;
  const ushort_t* Ag = Wt + (size_t)(row0 + srow) * FF + skcol;
  const ushort_t* Bg = X + (size_t)(col0 + srow) * FF + skcol;
  ushort_t* AsW = &As[w * 1024];
  ushort_t* BsW = &Bs[w * 1024];

  int m_l = l & 15, kq = (l >> 4) * 8;
  const ushort_t* ArdA = &As[(wr * 64 + m_l) * 32 + kq];
  const ushort_t* BrdB = &Bs[(wc * 64 + m_l) * 32 + kq];

  for (int k0 = 0; k0 < FF; k0 += 32) {
    gload_lds16(Ag + k0, AsW);
    gload_lds16(Ag + (size_t)16 * FF + k0, AsW + 512);
    gload_lds16(Bg + k0, BsW);
    gload_lds16(Bg + (size_t)16 * FF + k0, BsW + 512);
    __syncthreads();
    bf16x8 af[4], bfr[4];
    #pragma unroll
    for (int t = 0; t < 4; t++) {
      af[t]  = *(const bf16x8*)(ArdA + t * 16 * 32);
      bfr[t] = *(const bf16x8*)(BrdB + t * 16 * 32);
    }
    #pragma unroll
    for (int mt = 0; mt < 4; mt++)
      #pragma unroll
      for (int nt = 0; nt < 4; nt++)
        acc[mt][nt] = __builtin_amdgcn_mfma_f32_16x16x32_bf16(af[mt], bfr[nt], acc[mt][nt], 0, 0, 0);
    __syncthreads();
  }

  // epilogue: D[m=feature][n=node]; col=lane&15=node, row=quad*4+reg=feature
  int head = (row0 + wr * 64) >> 6;
  int rq = (l >> 4) * 4, cl = l & 15;
  float ds[4] = {0.f, 0.f, 0.f, 0.f}, dd[4] = {0.f, 0.f, 0.f, 0.f};
  #pragma unroll
  for (int mt = 0; mt < 4; mt++) {
    #pragma unroll
    for (int r = 0; r < 4; r++) {
      int f = row0 + wr * 64 + mt * 16 + rq + r;
      float a_s = a_src[f], a_d = a_dst[f];
      #pragma unroll
      for (int nt = 0; nt < 4; nt++) {
        float v = acc[mt][nt][r];
        ds[nt] += v * a_s;
        dd[nt] += v * a_d;
        int n = col0 + wc * 64 + nt * 16 + cl;
        hT[(size_t)f * NTP + n] = f2bf(v);
      }
    }
  }
  #pragma unroll
  for (int nt = 0; nt < 4; nt++) {
    ds[nt] += __shfl_xor(ds[nt], 16, 64); ds[nt] += __shfl_xor(ds[nt], 32, 64);
    dd[nt] += __shfl_xor(dd[nt], 16, 64); dd[nt] += __shfl_xor(dd[nt], 32, 64);
  }
  if (l < 16) {
    #pragma unroll
    for (int nt = 0; nt < 4; nt++) {
      int n = col0 + wc * 64 + nt * 16 + l;
      ssg[(size_t)n * 8 + head] = ds[nt];
      sdg[(size_t)n * 8 + head] = dd[nt];
    }
  }
}

// Fused GAT layer (one block per graph,head). Layers 2,3: ht staged from
// transposed global hT (coalesced, conflict-free), dots precomputed by GEMM.
// Layer 1: conv1 + in-block dots (old dual-write path). Softmax: bounded-max
// scatter with fp32 LDS atomics across all 256 threads (no CSR).
__global__ __launch_bounds__(256) void k_gatm(
    const ushort_t* __restrict__ hT,     // layers 2,3
    const float* __restrict__ xin, const float* __restrict__ W1,  // layer 1
    ushort_t* __restrict__ xout,
    const float* __restrict__ a_src, const float* __restrict__ a_dst,  // layer 1
    const float* __restrict__ ssg, const float* __restrict__ sdg,      // layers 2,3
    const int* __restrict__ ei, const float* __restrict__ eattr,
    const float* __restrict__ lattr, const float* __restrict__ gmm,
    const float* __restrict__ wdot_all, const float* __restrict__ bias,
    int layer, int self_loops) {
  int g = blockIdx.x, hd = blockIdx.y, tid = threadIdx.x;
  int w = tid >> 6, lane = tid & 63;
  const bool l1 = (W1 != nullptr);

  __shared__ __align__(16) ushort_t ht[64 * 72];   // ht[c][s] (l1: s ^ (c&56))
  __shared__ __align__(16) float P[50 * 68];       // union: hrow bf16 (layer 1)
  __shared__ __align__(16) ushort_t Am[64 * 72];   // alpha bf16 [d][s]
  __shared__ __align__(16) ushort_t ab[16 * 72];   // rows 0/1: a_src/a_dst (l1)
  __shared__ float ssl[64], sdl[64], lat[64];

  float wdot = wdot_all[layer * 8 + hd];
  float minEA = gmm[g * 2], maxEA = gmm[g * 2 + 1];
  float cmax = fmaxf(wdot * maxEA, wdot * minEA);
  if (tid < NP) lat[tid] = lattr[g * NP + tid];
  int m_l = lane & 15, kq8 = (lane >> 4) * 8;

  if (l1) {
    if (tid < 64) ab[tid] = f2bf(a_src[hd * 64 + tid]);
    else if (tid < 128) ab[72 + (tid - 64)] = f2bf(a_dst[hd * 64 + (tid - 64)]);
    { uint4* z = (uint4*)ht; uint4 zz = make_uint4(0u, 0u, 0u, 0u);
      for (int i = tid; i < 576; i += 256) z[i] = zz; }
    float w1c0 = W1[hd * 64 + lane], w1c1 = W1[512 + hd * 64 + lane],
          w1c2 = W1[1024 + hd * 64 + lane], w1c3 = W1[1536 + hd * 64 + lane];
    __syncthreads();
    ushort_t* hrow = (ushort_t*)P;
    #pragma unroll
    for (int i = 0; i < 13; i++) {
      int s = w + 4 * i;
      if (s < NP) {
        const float4 xv = *(const float4*)(xin + (size_t)(g * NP + s) * 4);
        float hv = xv.x * w1c0 + xv.y * w1c1 + xv.z * w1c2 + xv.w * w1c3;
        ushort_t hb = f2bf(hv);
        hrow[s * 72 + lane] = hb;
        ht[lane * 72 + (s ^ (lane & 56))] = hb;
      }
    }
    __syncthreads();
    { int s0 = w * 16;
      f32x4 dacc = (f32x4){0.f, 0.f, 0.f, 0.f};
      #pragma unroll
      for (int kc = 0; kc < 2; kc++) {
        bf16x8 a = *(const bf16x8*)(&ab[m_l * 72 + kc * 32 + kq8]);
        bf16x8 b = *(const bf16x8*)(&hrow[(s0 + m_l) * 72 + kc * 32 + kq8]);
        dacc = __builtin_amdgcn_mfma_f32_16x16x32_bf16(a, b, dacc, 0, 0, 0);
      }
      if (lane < 16) { ssl[s0 + lane] = dacc[0]; sdl[s0 + lane] = dacc[1]; }
    }
    __syncthreads();
    if (tid >= NP && tid < 64) { ssl[tid] = -1e30f; sdl[tid] = 0.f; }
  } else {
    // stage ht[c][0..63] from hT (cols >= 50 garbage-but-finite; Am cols are 0)
    for (int i = tid; i < 2048; i += 256) {
      int c = i >> 5, q = i & 31;
      *(unsigned int*)(&ht[c * 72 + q * 2]) =
          *(const unsigned int*)(&hT[(size_t)(hd * 64 + c) * NTP + g * NP + q * 2]);
    }
    if (tid < 64) {
      ssl[tid] = (tid < NP) ? ssg[(size_t)(g * NP + tid) * 8 + hd] : -1e30f;
      sdl[tid] = (tid < NP) ? sdg[(size_t)(g * NP + tid) * 8 + hd] : 0.f;
    }
  }
  // zero P (850 uint4 = 13600 B)
  { uint4* z = (uint4*)P; uint4 zz = make_uint4(0u, 0u, 0u, 0u);
    for (int i = tid; i < 850; i += 256) z[i] = zz; }
  __syncthreads();

  // per-wave maxS over ssl
  float mv = ssl[lane];
  #pragma unroll
  for (int m = 32; m >= 1; m >>= 1) mv = fmaxf(mv, __shfl_xor(mv, m, 64));

  // edge scatter: p = exp(lr(al) - m_d), m_d = lr(maxS + sdl[d] + cmax) >= row max
  for (int e = tid; e < EPG; e += 256) {
    int eg = g * EPG + e;
    int s = ei[eg] - g * NP;
    int d = ei[EE + eg] - g * NP;
    float al = ssl[s] + sdl[d] + eattr[eg] * wdot;
    al = al > 0.f ? al : 0.2f * al;
    float ub = mv + sdl[d] + cmax;
    ub = ub > 0.f ? ub : 0.2f * ub;
    atomicAdd(&P[d * 68 + s], __expf(al - ub));
  }
  if (self_loops && tid < NP) {
    int d = tid;
    float al = ssl[d] + sdl[d] + lat[d] * wdot;
    al = al > 0.f ? al : 0.2f * al;
    float ub = mv + sdl[d] + cmax;
    ub = ub > 0.f ? ub : 0.2f * ub;
    atomicAdd(&P[d * 68 + d], __expf(al - ub));
  }
  __syncthreads();

  // normalize -> bf16 Am (rows/cols >= 50 exact zero)
  { int d = tid >> 2, part = tid & 3;
    if (d < NP) {
      f32x4 v0 = *(const f32x4*)(&P[d * 68 + part * 16 + 0]);
      f32x4 v1 = *(const f32x4*)(&P[d * 68 + part * 16 + 4]);
      f32x4 v2 = *(const f32x4*)(&P[d * 68 + part * 16 + 8]);
      f32x4 v3 = *(const f32x4*)(&P[d * 68 + part * 16 + 12]);
      float sm = (v0[0] + v0[1] + v0[2] + v0[3]) + (v1[0] + v1[1] + v1[2] + v1[3])
               + (v2[0] + v2[1] + v2[2] + v2[3]) + (v3[0] + v3[1] + v3[2] + v3[3]);
      sm += __shfl_xor(sm, 1, 64);
      sm += __shfl_xor(sm, 2, 64);
      float inv = 1.f / (sm + 1e-16f);
      union { ushort_t u[8]; uint4 q; } p0, p1;
      p0.u[0] = f2bf(v0[0] * inv); p0.u[1] = f2bf(v0[1] * inv);
      p0.u[2] = f2bf(v0[2] * inv); p0.u[3] = f2bf(v0[3] * inv);
      p0.u[4] = f2bf(v1[0] * inv); p0.u[5] = f2bf(v1[1] * inv);
      p0.u[6] = f2bf(v1[2] * inv); p0.u[7] = f2bf(v1[3] * inv);
      p1.u[0] = f2bf(v2[0] * inv); p1.u[1] = f2bf(v2[1] * inv);
      p1.u[2] = f2bf(v2[2] * inv); p1.u[3] = f2bf(v2[3] * inv);
      p1.u[4] = f2bf(v3[0] * inv); p1.u[5] = f2bf(v3[1] * inv);
      p1.u[6] = f2bf(v3[2] * inv); p1.u[7] = f2bf(v3[3] * inv);
      *(uint4*)(&Am[d * 72 + part * 16]) = p0.q;
      *(uint4*)(&Am[d * 72 + part * 16 + 8]) = p1.q;
    } else {
      uint4 zz = make_uint4(0u, 0u, 0u, 0u);
      *(uint4*)(&Am[d * 72 + part * 16]) = zz;
      *(uint4*)(&Am[d * 72 + part * 16 + 8]) = zz;
    }
  }
  __syncthreads();

  // out MFMA: D[m=c][n=d] = ht @ Am^T; wave w owns d in [w*16, w*16+16)
  int d0 = w * 16;
  f32x4 acc[4];
  #pragma unroll
  for (int ct = 0; ct < 4; ct++) acc[ct] = (f32x4){0.f, 0.f, 0.f, 0.f};
  #pragma unroll
  for (int kc = 0; kc < 2; kc++) {
    int kb = kc * 32 + kq8;
    bf16x8 bfrag = *(const bf16x8*)(&Am[(d0 + m_l) * 72 + kb]);
    #pragma unroll
    for (int ct = 0; ct < 4; ct++) {
      int m = ct * 16 + m_l;
      int ka = l1 ? (kb ^ (m & 56)) : kb;
      bf16x8 afrag = *(const bf16x8*)(&ht[m * 72 + ka]);
      acc[ct] = __builtin_amdgcn_mfma_f32_16x16x32_bf16(afrag, bfrag, acc[ct], 0, 0, 0);
    }
  }

  int d = d0 + m_l, rq = (lane >> 4) * 4;
  if (d < NP) {
    #pragma unroll
    for (int ct = 0; ct < 4; ct++) {
      int cb = ct * 16 + rq;
      const float4 bv = *(const float4*)(&bias[hd * 64 + cb]);
      union { ushort_t u[4]; uint2 v; } pk;
      pk.u[0] = f2bf(fmaxf(acc[ct][0] + bv.x, 0.f));
      pk.u[1] = f2bf(fmaxf(acc[ct][1] + bv.y, 0.f));
      pk.u[2] = f2bf(fmaxf(acc[ct][2] + bv.z, 0.f));
      pk.u[3] = f2bf(fmaxf(acc[ct][3] + bv.w, 0.f));
      *(uint2*)(&xout[(size_t)(g * NP + d) * FF + hd * 64 + cb]) = pk.v;
    }
  }
}

// generic bf16 MFMA GEMM (row-major C fp32) — used for the GRU input GEMM
__global__ __launch_bounds__(256) void k_bgemm(
    const ushort_t* __restrict__ A, const ushort_t* __restrict__ Bt,
    const float* __restrict__ bias, float* __restrict__ C,
    int M, int N, int K) {
  __shared__ ushort_t As[128 * 32];
  __shared__ ushort_t Bs[128 * 32];
  int tid = threadIdx.x;
  int w = tid >> 6, l = tid & 63;
  int row0 = blockIdx.y * 128, col0 = blockIdx.x * 128;
  int wr = w >> 1, wc = w & 1;

  f32x4 acc[4][4];
  #pragma unroll
  for (int i = 0; i < 4; i++)
    #pragma unroll
    for (int j = 0; j < 4; j++) acc[i][j] = (f32x4){0.f, 0.f, 0.f, 0.f};

  int srow = w * 32 + (l >> 2);
  int skcol = (l & 3) * 8;
  const ushort_t* Ag = A + (size_t)(row0 + srow) * K + skcol;
  const ushort_t* Bg = Bt + (size_t)(col0 + srow) * K + skcol;
  ushort_t* AsW = &As[w * 1024];
  ushort_t* BsW = &Bs[w * 1024];

  int m_l = l & 15, kq = (l >> 4) * 8;
  const ushort_t* ArdA = &As[(wr * 64 + m_l) * 32 + kq];
  const ushort_t* BrdB = &Bs[(wc * 64 + m_l) * 32 + kq];

  for (int k0 = 0; k0 < K; k0 += 32) {
    gload_lds16(Ag + k0, AsW);
    gload_lds16(Ag + (size_t)16 * K + k0, AsW + 512);
    gload_lds16(Bg + k0, BsW);
    gload_lds16(Bg + (size_t)16 * K + k0, BsW + 512);
    __syncthreads();
    bf16x8 af[4], bfr[4];
    #pragma unroll
    for (int t = 0; t < 4; t++) {
      af[t]  = *(const bf16x8*)(ArdA + t * 16 * 32);
      bfr[t] = *(const bf16x8*)(BrdB + t * 16 * 32);
    }
    #pragma unroll
    for (int mt = 0; mt < 4; mt++)
      #pragma unroll
      for (int nt = 0; nt < 4; nt++)
        acc[mt][nt] = __builtin_amdgcn_mfma_f32_16x16x32_bf16(af[mt], bfr[nt], acc[mt][nt], 0, 0, 0);
    __syncthreads();
  }

  int cl = l & 15, rq = (l >> 4) * 4;
  #pragma unroll
  for (int mt = 0; mt < 4; mt++) {
    #pragma unroll
    for (int nt = 0; nt < 4; nt++) {
      int col = col0 + wc * 64 + nt * 16 + cl;
      float bv = bias ? bias[col] : 0.f;
      #pragma unroll
      for (int r = 0; r < 4; r++) {
        int row = row0 + wr * 64 + mt * 16 + rq + r;
        C[(size_t)row * N + col] = acc[mt][nt][r] + bv;
      }
    }
  }
}

// graph mean pool + GRU input sequence [B,5,1024]=[agent|graph]; bf16 in/out
__global__ void k_pool(const ushort_t* __restrict__ x3, ushort_t* __restrict__ combined) {
  int b = blockIdx.x, tid = threadIdx.x;   // 256 threads
  float a0 = 0.f, a1 = 0.f;
  for (int n = 0; n < NP; n++) {
    const ushort_t* r = x3 + (size_t)(b * NP + n) * FF;
    a0 += bf2f(r[tid]); a1 += bf2f(r[tid + 256]);
  }
  a0 *= (1.f / NP); a1 *= (1.f / NP);
  ushort_t b0 = f2bf(a0), b1v = f2bf(a1);
  for (int t = 0; t < 5; t++) {
    ushort_t* cb = combined + (size_t)(b * 5 + t) * GRUIN;
    const ushort_t* ag = x3 + (size_t)(b * NP + t) * FF;
    cb[tid] = ag[tid];
    cb[tid + 256] = ag[tid + 256];
    cb[512 + tid] = b0;
    cb[768 + tid] = b1v;
  }
}

// GRU: one block per batch element, 5 sequential steps. gi_all already has bih.
__global__ void k_gru(const float* __restrict__ gi_all, const float* __restrict__ h0,
                      const float* __restrict__ Whh, const float* __restrict__ bhh,
                      float* __restrict__ gru_out, float* __restrict__ hlast) {
  int b = blockIdx.x, tid = threadIdx.x;   // 384 threads
  __shared__ float hl[GRUH];
  __shared__ float ghb[384];
  if (tid < GRUH) hl[tid] = h0[b * GRUH + tid];
  for (int t = 0; t < 5; t++) {
    __syncthreads();
    float acc = bhh[tid];
    for (int k = 0; k < GRUH; k++) acc += hl[k] * Whh[k * 384 + tid];
    ghb[tid] = acc;
    __syncthreads();
    if (tid < GRUH) {
      const float* gi = gi_all + (size_t)(b * 5 + t) * 384;
      float r = 1.f / (1.f + expf(-(gi[tid] + ghb[tid])));
      float z = 1.f / (1.f + expf(-(gi[128 + tid] + ghb[128 + tid])));
      float nn = tanhf(gi[256 + tid] + r * ghb[256 + tid]);
      float hn = (1.f - z) * nn + z * hl[tid];
      gru_out[(size_t)(b * 5 + t) * GRUH + tid] = hn;
      hl[tid] = hn;
    }
  }
  __syncthreads();
  if (tid < GRUH) hlast[b * GRUH + tid] = hl[tid];
}

// fc1(relu) + fc2 + action_std, one block (64 thr) per (b,t) row
__global__ void k_fc(const float* __restrict__ gru_out, const float* __restrict__ fc1W,
                     const float* __restrict__ fc1b, const float* __restrict__ fc2W,
                     const float* __restrict__ fc2b, const float* __restrict__ log_std,
                     float* __restrict__ dout) {
  int row = blockIdx.x, tid = threadIdx.x;   // 64 threads
  __shared__ float gbuf[GRUH];
  __shared__ float f1[64];
  gbuf[tid] = gru_out[(size_t)row * GRUH + tid];
  gbuf[tid + 64] = gru_out[(size_t)row * GRUH + 64 + tid];
  __syncthreads();
  float acc = fc1b[tid];
  for (int k = 0; k < GRUH; k++) acc += gbuf[k] * fc1W[k * 64 + tid];
  f1[tid] = fmaxf(acc, 0.f);
  __syncthreads();
  if (tid < 3) {
    float o = fc2b[tid];
    for (int j = 0; j < 64; j++) o += f1[j] * fc2W[j * 3 + tid];
    dout[row * 3 + tid] = o;
    float ls = log_std[tid];
    ls = fminf(fmaxf(ls, -20.f), 2.f);
    dout[7680 + row * 3 + tid] = expf(ls);
  }
}

extern "C" void kernel_launch(void* const* d_in, const int* in_sizes, int n_in,
                              void* d_out, int out_size, void* d_ws, size_t ws_size,
                              hipStream_t stream) {
  const float* x      = (const float*)d_in[0];
  const int*   ei     = (const int*)d_in[1];
  const float* eattr  = (const float*)d_in[2];
  const float* hstate = (const float*)d_in[3];
  const float* W1  = (const float*)d_in[4];
  const float* as1 = (const float*)d_in[5];
  const float* ad1 = (const float*)d_in[6];
  const float* We1 = (const float*)d_in[7];
  const float* ae1 = (const float*)d_in[8];
  const float* b1  = (const float*)d_in[9];
  const float* W2  = (const float*)d_in[10];
  const float* as2 = (const float*)d_in[11];
  const float* ad2 = (const float*)d_in[12];
  const float* We2 = (const float*)d_in[13];
  const float* ae2 = (const float*)d_in[14];
  const float* b2  = (const float*)d_in[15];
  const float* W3  = (const float*)d_in[16];
  const float* as3 = (const float*)d_in[17];
  const float* ad3 = (const float*)d_in[18];
  const float* We3 = (const float*)d_in[19];
  const float* ae3 = (const float*)d_in[20];
  const float* b3  = (const float*)d_in[21];
  const float* Wih = (const float*)d_in[22];
  const float* Whh = (const float*)d_in[23];
  const float* bih = (const float*)d_in[24];
  const float* bhh = (const float*)d_in[25];
  const float* fc1W = (const float*)d_in[26];
  const float* fc1b = (const float*)d_in[27];
  const float* fc2W = (const float*)d_in[28];
  const float* fc2b = (const float*)d_in[29];
  const float* lstd = (const float*)d_in[30];

  float* ws = (float*)d_ws;
  ushort_t* xbf = (ushort_t*)ws;                     // 13,107,200 us
  ushort_t* hT  = (ushort_t*)(ws + 6553600);         // 512*25664 = 13,139,968 us
  float* p = ws + 6553600 + 6569984;
  float* ssg   = p;           p += 204800;
  float* sdg   = p;           p += 204800;
  float* lattr = p;           p += 25600;
  float* gmm   = p;           p += 1024;
  float* wdot  = p;           p += 32;
  ushort_t* w2t  = (ushort_t*)p;  p += 131072;   // 262144 us
  ushort_t* w3t  = (ushort_t*)p;  p += 131072;
  ushort_t* wiht = (ushort_t*)p;  p += 196608;   // 393216 us
  ushort_t* cbf  = (ushort_t*)p;  p += 1310720;  // 2,621,440 us
  float* gi_all  = p;         p += 983040;       // [2560][384]
  float* gru_out = p;         p += 327680;
  float* dout = (float*)d_out;

  k_wedot<<<3, 512, 0, stream>>>(We1, ae1, We2, ae2, We3, ae3, wdot);
  k_lattr<<<BB, 256, 0, stream>>>(ei, eattr, lattr, gmm);
  k_cvt_t<<<dim3(16, 16), 256, 0, stream>>>(W2, w2t, FF, FF);
  k_cvt_t<<<dim3(16, 16), 256, 0, stream>>>(W3, w3t, FF, FF);
  k_cvt_t<<<dim3(12, 32), 256, 0, stream>>>(Wih, wiht, GRUIN, 384);

  // layer 1: fused conv1 + in-block dots + gat -> xbf
  k_gatm<<<dim3(BB, HH), 256, 0, stream>>>(nullptr, x, W1, xbf, as1, ad1,
                                           nullptr, nullptr, ei, eattr,
                                           lattr, gmm, wdot, b1, 0, 0);
  // layer 2: hT = W2t @ x1^T (+ fused dots); gat -> xbf
  k_bgemmT<<<dim3(200, 4), 256, 0, stream>>>(w2t, xbf, as2, ad2, hT, ssg, sdg);
  k_gatm<<<dim3(BB, HH), 256, 0, stream>>>(hT, nullptr, nullptr, xbf, nullptr, nullptr,
                                           ssg, sdg, ei, eattr,
                                           lattr, gmm, wdot, b2, 1, 1);
  // layer 3
  k_bgemmT<<<dim3(200, 4), 256, 0, stream>>>(w3t, xbf, as3, ad3, hT, ssg, sdg);
  k_gatm<<<dim3(BB, HH), 256, 0, stream>>>(hT, nullptr, nullptr, xbf, nullptr, nullptr,
                                           ssg, sdg, ei, eattr,
                                           lattr, gmm, wdot, b3, 2, 1);

  // pool (bf16 combined) + GRU input GEMM (adds bih)
  k_pool<<<BB, 256, 0, stream>>>(xbf, cbf);
  k_bgemm<<<dim3(3, 20), 256, 0, stream>>>(cbf, wiht, bih, gi_all, 2560, 384, GRUIN);

  // GRU scan + heads
  k_gru<<<BB, 384, 0, stream>>>(gi_all, hstate, Whh, bhh, gru_out, dout + 15360);
  k_fc<<<2560, 64, 0, stream>>>(gru_out, fc1W, fc1b, fc2W, fc2b, lstd, dout);
}